// Round 4
// baseline (1151.132 us; speedup 1.0000x reference)
//
#include <hip/hip_runtime.h>
#include <math.h>

// Problem constants (B=1)
#define T_ 2048
#define D_ 1024
#define H_ 16
#define N_ 64
#define F_ 4096
#define NCHUNK 32
#define CLEN 64

typedef __attribute__((ext_vector_type(8))) short bf16x8;
typedef __attribute__((ext_vector_type(4))) float f32x4;

static __device__ __forceinline__ float sigf(float x) { return 1.0f / (1.0f + __expf(-x)); }

static __device__ __forceinline__ ushort f2bf(float f) {
    union { float f; unsigned u; } c; c.f = f;
    unsigned r = (c.u + 0x7FFFu + ((c.u >> 16) & 1u)) >> 16;
    return (ushort)r;
}
static __device__ __forceinline__ float bf2f(ushort h) {
    union { unsigned u; float f; } c; c.u = ((unsigned)h) << 16;
    return c.f;
}

static __device__ __forceinline__ void st4(float* p, float4 v) { *(float4*)p = v; }
static __device__ __forceinline__ void st4(ushort* p, float4 v) {
    ushort4 o; o.x = f2bf(v.x); o.y = f2bf(v.y); o.z = f2bf(v.z); o.w = f2bf(v.w);
    *(ushort4*)p = o;
}
static __device__ __forceinline__ void stC(float* p, float v) { *p = v; }
static __device__ __forceinline__ void stC(ushort* p, float v) { *p = f2bf(v); }

// ---------------------------------------------------------------------------
// RMSNorm: one block per token row. out = w * x * rsqrt(mean(x^2)+eps)
// ---------------------------------------------------------------------------
template <typename OutT>
__global__ __launch_bounds__(256) void rmsnorm_kernel(const float* __restrict__ x,
                                                      const float* __restrict__ w,
                                                      OutT* __restrict__ out,
                                                      float* __restrict__ last) {
    const int t = blockIdx.x;
    const int tid = threadIdx.x;
    const float4* xr = (const float4*)(x + (size_t)t * D_);
    float4 v = xr[tid];
    float ss = v.x * v.x + v.y * v.y + v.z * v.z + v.w * v.w;
    ss += __shfl_xor(ss, 1);
    ss += __shfl_xor(ss, 2);
    ss += __shfl_xor(ss, 4);
    ss += __shfl_xor(ss, 8);
    ss += __shfl_xor(ss, 16);
    ss += __shfl_xor(ss, 32);
    __shared__ float red[4];
    if ((tid & 63) == 0) red[tid >> 6] = ss;
    __syncthreads();
    float tot = red[0] + red[1] + red[2] + red[3];
    float scale = rsqrtf(tot * (1.0f / (float)D_) + 1e-6f);
    float4 wv = ((const float4*)w)[tid];
    float4 o;
    o.x = wv.x * v.x * scale;
    o.y = wv.y * v.y * scale;
    o.z = wv.z * v.z * scale;
    o.w = wv.w * v.w * scale;
    st4(out + (size_t)t * D_ + tid * 4, o);
    if (last != nullptr && t == T_ - 1) ((float4*)last)[tid] = o;
}

// ---------------------------------------------------------------------------
// Token shift -> six bf16 activation buffers (GEMM A operands).
// ---------------------------------------------------------------------------
__global__ __launch_bounds__(256) void shift_kernel(
    const float* __restrict__ xn, const float* __restrict__ x_prev,
    const float* __restrict__ cr, const float* __restrict__ cw, const float* __restrict__ ck,
    const float* __restrict__ cv, const float* __restrict__ ca, const float* __restrict__ cg,
    ushort* __restrict__ xr, ushort* __restrict__ xw, ushort* __restrict__ xk,
    ushort* __restrict__ xv, ushort* __restrict__ xa, ushort* __restrict__ xg) {
    const int i = blockIdx.x * 256 + threadIdx.x;  // float4 index over T*256
    const int t = i >> 8, j = i & 255;
    const float4* xn4 = (const float4*)xn;
    float4 cur = xn4[i];
    float4 prev = (t == 0) ? ((const float4*)x_prev)[j] : xn4[i - 256];
    float4 xx;
    xx.x = prev.x - cur.x;
    xx.y = prev.y - cur.y;
    xx.z = prev.z - cur.z;
    xx.w = prev.w - cur.w;
#define APPLY(dst, c)                                   \
    {                                                   \
        float4 cc = ((const float4*)c)[j];              \
        float4 o;                                       \
        o.x = cur.x + xx.x * cc.x;                      \
        o.y = cur.y + xx.y * cc.y;                      \
        o.z = cur.z + xx.z * cc.z;                      \
        o.w = cur.w + xx.w * cc.w;                      \
        st4(dst + (size_t)i * 4, o);                    \
    }
    APPLY(xr, cr)
    APPLY(xw, cw)
    APPLY(xk, ck)
    APPLY(xv, cv)
    APPLY(xa, ca)
    APPLY(xg, cg)
#undef APPLY
}

// ---------------------------------------------------------------------------
// Weight transpose + cast: in [K,N] fp32 -> out [N,K] bf16. 32x32 tiles.
// ---------------------------------------------------------------------------
__global__ __launch_bounds__(256) void transpose_cast(const float* __restrict__ in,
                                                      ushort* __restrict__ out, int K, int N) {
    __shared__ float tile[32][33];
    const int tx = threadIdx.x & 31, ty = threadIdx.x >> 5;  // 32 x 8
    const int n0 = blockIdx.x * 32, k0 = blockIdx.y * 32;
#pragma unroll
    for (int i = 0; i < 4; i++)
        tile[ty + i * 8][tx] = in[(size_t)(k0 + ty + i * 8) * N + n0 + tx];
    __syncthreads();
#pragma unroll
    for (int i = 0; i < 4; i++)
        out[(size_t)(n0 + ty + i * 8) * K + k0 + tx] = f2bf(tile[tx][ty + i * 8]);
}

// ---------------------------------------------------------------------------
// bf16 MFMA GEMM: C[M,Ntot] = epi(A[M,K] @ BT[Ntot,K]^T).
// 128x128 tile, block 256 (4 waves, 2x2), BK=32, mfma_f32_16x16x32_bf16.
// epi: 0 none, 1 +res, 2 silu, 3 tanh, 4 sig(v), 5 sig(bias+v),
//      6 exp(-e^-0.5*sig(bias+v)) [decay], 7 res+(res2-res)*sig(bias+v) [vlerp]
// ---------------------------------------------------------------------------
template <typename OutT>
__global__ __launch_bounds__(256) void mfma_gemm(
    const ushort* __restrict__ A, const ushort* __restrict__ BT, OutT* __restrict__ C,
    const float* __restrict__ res, const float* __restrict__ res2, const float* __restrict__ bias,
    int M, int Ntot, int K, int epi) {
    __shared__ ushort As[128 * 40];
    __shared__ ushort Bs[128 * 40];
    const int tid = threadIdx.x;
    const int wave = tid >> 6, lane = tid & 63;
    const int wr = wave >> 1, wc = wave & 1;
    const int lrow = lane & 15, quad = lane >> 4;
    const int m0 = blockIdx.y * 128, n0 = blockIdx.x * 128;
    const int sr = tid >> 2;           // staging row 0..63 (and +64)
    const int sc = (tid & 3) << 3;     // staging k offset in elements {0,8,16,24}

    f32x4 acc[4][4] = {};

    for (int k0 = 0; k0 < K; k0 += 32) {
        const float4 av0 = *(const float4*)(A + (size_t)(m0 + sr) * K + k0 + sc);
        const float4 av1 = *(const float4*)(A + (size_t)(m0 + sr + 64) * K + k0 + sc);
        float4 bv0 = make_float4(0.f, 0.f, 0.f, 0.f);
        float4 bv1 = make_float4(0.f, 0.f, 0.f, 0.f);
        if (n0 + sr < Ntot) bv0 = *(const float4*)(BT + (size_t)(n0 + sr) * K + k0 + sc);
        if (n0 + sr + 64 < Ntot) bv1 = *(const float4*)(BT + (size_t)(n0 + sr + 64) * K + k0 + sc);
        __syncthreads();  // previous iter's LDS reads done
        *(float4*)&As[sr * 40 + sc] = av0;
        *(float4*)&As[(sr + 64) * 40 + sc] = av1;
        *(float4*)&Bs[sr * 40 + sc] = bv0;
        *(float4*)&Bs[(sr + 64) * 40 + sc] = bv1;
        __syncthreads();
        bf16x8 af[4], bfr[4];
#pragma unroll
        for (int mi = 0; mi < 4; mi++)
            af[mi] = *(const bf16x8*)&As[(wr * 64 + mi * 16 + lrow) * 40 + quad * 8];
#pragma unroll
        for (int ni = 0; ni < 4; ni++)
            bfr[ni] = *(const bf16x8*)&Bs[(wc * 64 + ni * 16 + lrow) * 40 + quad * 8];
#pragma unroll
        for (int mi = 0; mi < 4; mi++)
#pragma unroll
            for (int ni = 0; ni < 4; ni++)
                acc[mi][ni] = __builtin_amdgcn_mfma_f32_16x16x32_bf16(af[mi], bfr[ni], acc[mi][ni], 0, 0, 0);
    }

#pragma unroll
    for (int mi = 0; mi < 4; mi++) {
#pragma unroll
        for (int r = 0; r < 4; r++) {
            const int row = m0 + wr * 64 + mi * 16 + quad * 4 + r;
#pragma unroll
            for (int ni = 0; ni < 4; ni++) {
                const int col = n0 + wc * 64 + ni * 16 + lrow;
                if (col < Ntot) {
                    const size_t idx = (size_t)row * Ntot + col;
                    float val = acc[mi][ni][r];
                    switch (epi) {
                        case 1: val += res[idx]; break;
                        case 2: val = val * sigf(val); break;
                        case 3: val = tanhf(val); break;
                        case 4: val = sigf(val); break;
                        case 5: val = sigf(bias[col] + val); break;
                        case 6: val = __expf(-0.60653065971263342f * sigf(bias[col] + val)); break;
                        case 7: {
                            float vr = res[idx];
                            val = vr + (res2[idx] - vr) * sigf(bias[col] + val);
                        } break;
                        default: break;
                    }
                    stC(&C[idx], val);
                }
            }
        }
    }
}

// ---------------------------------------------------------------------------
// kk = normalize_per_head(k * k_k); mb = -kk*a_sig; k *= (1+(a-1)*k_a).
// ---------------------------------------------------------------------------
__global__ __launch_bounds__(64) void kk_kernel(float* __restrict__ k,
                                                const float* __restrict__ a_sig,
                                                const float* __restrict__ k_k,
                                                const float* __restrict__ k_a,
                                                float* __restrict__ kk,
                                                float* __restrict__ mb) {
    const int b = blockIdx.x;
    const int t = b >> 4, h = b & 15;
    const int lane = threadIdx.x;
    const size_t idx = (size_t)t * D_ + h * N_ + lane;
    const int wi = h * N_ + lane;
    const float kraw = k[idx];
    const float kv = kraw * k_k[wi];
    float ss = kv * kv;
    ss += __shfl_xor(ss, 1);
    ss += __shfl_xor(ss, 2);
    ss += __shfl_xor(ss, 4);
    ss += __shfl_xor(ss, 8);
    ss += __shfl_xor(ss, 16);
    ss += __shfl_xor(ss, 32);
    const float nrm = fmaxf(sqrtf(ss), 1e-12f);
    const float kkn = kv / nrm;
    kk[idx] = kkn;
    mb[idx] = -kkn * a_sig[idx];
    k[idx] = kraw * (1.0f + (a_sig[idx] - 1.0f) * k_a[wi]);
}

// ---------------------------------------------------------------------------
// Chunked scan pass 1, lane = row layout.
// One wave per (chunk, head, {P|L}): lane i owns row i of the 64x64 matrix in
// 64 VGPRs. Coefficient vectors (d, kk, mb, k, r) are wave-uniform per step ->
// scalar(s_load)/broadcast loads, no shuffles, no LDS. sap and the output dot
// are in-lane 64-FMA reductions with 4-way split accumulators.
// Grid: NCHUNK*H*2 blocks of 64 threads. isp (P) evolves from I with v=0;
// L evolves from 0 with the v k^T term. Dots: P -> zbuf, L -> olbuf.
// ---------------------------------------------------------------------------
__global__ __launch_bounds__(64) void scan_pass1(
    const float* __restrict__ gR, const float* __restrict__ gD, const float* __restrict__ gK,
    const float* __restrict__ gV, const float* __restrict__ gKK, const float* __restrict__ gMB,
    float* __restrict__ Pbuf, float* __restrict__ Lbuf,
    float* __restrict__ zbuf, float* __restrict__ olbuf) {
    const int bid = blockIdx.x;
    const bool isp = bid & 1;
    const int h = (bid >> 1) & 15;
    const int c = bid >> 5;
    const int lane = threadIdx.x;  // row index
    const int hb = h * N_;
    const int t0 = c * CLEN;

    float s[64];
#pragma unroll
    for (int j = 0; j < 64; j++) s[j] = (isp && j == lane) ? 1.0f : 0.0f;

    float* __restrict__ dotOut = isp ? zbuf : olbuf;

    for (int t = t0; t < t0 + CLEN; t++) {
        const float* __restrict__ cD = gD + (size_t)t * D_ + hb;
        const float* __restrict__ cK = gK + (size_t)t * D_ + hb;
        const float* __restrict__ cKK = gKK + (size_t)t * D_ + hb;
        const float* __restrict__ cMB = gMB + (size_t)t * D_ + hb;
        const float* __restrict__ cR = gR + (size_t)t * D_ + hb;

        // pass A: sap = sum_j s[j] * kk[j]  (in-lane, 4-way split)
        float sa0 = 0.f, sa1 = 0.f, sa2 = 0.f, sa3 = 0.f;
#pragma unroll
        for (int jb = 0; jb < 16; jb++) {
            const float4 kk4 = *(const float4*)(cKK + jb * 4);
            sa0 = fmaf(s[jb * 4 + 0], kk4.x, sa0);
            sa1 = fmaf(s[jb * 4 + 1], kk4.y, sa1);
            sa2 = fmaf(s[jb * 4 + 2], kk4.z, sa2);
            sa3 = fmaf(s[jb * 4 + 3], kk4.w, sa3);
        }
        const float sap = (sa0 + sa1) + (sa2 + sa3);
        const float vv = isp ? 0.0f : gV[(size_t)t * D_ + hb + lane];

        // pass B: s[j] = s[j]*d[j] + sap*mb[j] + vv*k[j]; o += s[j]*r[j]
        float o0 = 0.f, o1 = 0.f, o2 = 0.f, o3 = 0.f;
#pragma unroll
        for (int jb = 0; jb < 16; jb++) {
            const float4 d4 = *(const float4*)(cD + jb * 4);
            const float4 k4 = *(const float4*)(cK + jb * 4);
            const float4 mb4 = *(const float4*)(cMB + jb * 4);
            const float4 r4 = *(const float4*)(cR + jb * 4);
            float t0v = fmaf(sap, mb4.x, vv * k4.x);
            float t1v = fmaf(sap, mb4.y, vv * k4.y);
            float t2v = fmaf(sap, mb4.z, vv * k4.z);
            float t3v = fmaf(sap, mb4.w, vv * k4.w);
            s[jb * 4 + 0] = fmaf(s[jb * 4 + 0], d4.x, t0v);
            s[jb * 4 + 1] = fmaf(s[jb * 4 + 1], d4.y, t1v);
            s[jb * 4 + 2] = fmaf(s[jb * 4 + 2], d4.z, t2v);
            s[jb * 4 + 3] = fmaf(s[jb * 4 + 3], d4.w, t3v);
            o0 = fmaf(s[jb * 4 + 0], r4.x, o0);
            o1 = fmaf(s[jb * 4 + 1], r4.y, o1);
            o2 = fmaf(s[jb * 4 + 2], r4.z, o2);
            o3 = fmaf(s[jb * 4 + 3], r4.w, o3);
        }
        dotOut[(size_t)t * D_ + hb + lane] = (o0 + o1) + (o2 + o3);
    }

    float* __restrict__ sd = isp ? Pbuf : Lbuf;
    const size_t base = ((size_t)c * 16 + h) * 4096 + (size_t)lane * 64;
#pragma unroll
    for (int q = 0; q < 16; q++)
        *(float4*)(sd + base + q * 4) =
            make_float4(s[q * 4 + 0], s[q * 4 + 1], s[q * 4 + 2], s[q * 4 + 3]);
}

// ---------------------------------------------------------------------------
// Serial chunk combine: S_{c+1} = S_c @ P_c + L_c, S_0 = state_in.
// Stores S_start (transposed) per chunk for the fix pass; final -> state_out.
// Grid 64 = 16 heads x 4 row-groups of 16 rows.
// ---------------------------------------------------------------------------
__global__ __launch_bounds__(256) void scan_combine(
    const float* __restrict__ state_in, const float* __restrict__ Pbuf,
    const float* __restrict__ Lbuf, float* __restrict__ SstT, float* __restrict__ state_out) {
    const int h = blockIdx.x >> 2, rg = blockIdx.x & 3;
    const int tid = threadIdx.x;
    const int i = tid >> 4, j4 = (tid & 15) << 2;
    const int gi = rg * 16 + i;
    __shared__ float Sl[16][68];
    __shared__ float Pl[64][68];

    float4 sv = *(const float4*)(state_in + (size_t)h * 4096 + gi * 64 + j4);
    *(float4*)&Sl[i][j4] = sv;
    __syncthreads();

    for (int c = 0; c < NCHUNK; c++) {
        const size_t cb = ((size_t)c * 16 + h) * 4096;
        float4 scur = *(const float4*)&Sl[i][j4];
        // store S_start transposed: SstT[j][i] = S[i][j]
        SstT[cb + (size_t)(j4 + 0) * 64 + gi] = scur.x;
        SstT[cb + (size_t)(j4 + 1) * 64 + gi] = scur.y;
        SstT[cb + (size_t)(j4 + 2) * 64 + gi] = scur.z;
        SstT[cb + (size_t)(j4 + 3) * 64 + gi] = scur.w;
        // stage P_c
#pragma unroll
        for (int q = 0; q < 4; q++) {
            const int pr = (tid >> 4) + q * 16;
            *(float4*)&Pl[pr][j4] = *(const float4*)(Pbuf + cb + (size_t)pr * 64 + j4);
        }
        __syncthreads();
        float4 acc = *(const float4*)(Lbuf + cb + (size_t)gi * 64 + j4);
#pragma unroll 8
        for (int m = 0; m < 64; m++) {
            const float smv = Sl[i][m];
            const float4 p4 = *(const float4*)&Pl[m][j4];
            acc.x = fmaf(smv, p4.x, acc.x);
            acc.y = fmaf(smv, p4.y, acc.y);
            acc.z = fmaf(smv, p4.z, acc.z);
            acc.w = fmaf(smv, p4.w, acc.w);
        }
        __syncthreads();
        *(float4*)&Sl[i][j4] = acc;
        __syncthreads();
    }
    *(float4*)(state_out + (size_t)h * 4096 + gi * 64 + j4) = *(const float4*)&Sl[i][j4];
}

// ---------------------------------------------------------------------------
// Fix pass: o[t] = o_local[t] + S_start_c @ z[t] (per head).
// Grid 2048 = 128 token-groups (16 tokens) x 16 heads.
// ---------------------------------------------------------------------------
__global__ __launch_bounds__(256) void scan_fix(
    const float* __restrict__ zbuf, const float* __restrict__ olbuf,
    const float* __restrict__ SstT, float* __restrict__ o) {
    const int tg = blockIdx.x >> 4, h = blockIdx.x & 15;
    const int hb = h * N_;
    const int tid = threadIdx.x;
    const int tok = tid >> 4, i4 = (tid & 15) << 2;
    const int tbase = tg * 16;
    const int c = tbase >> 6;
    __shared__ float zl[16][68];
    __shared__ float Sl[64][68];

    *(float4*)&zl[tok][i4] = *(const float4*)(zbuf + (size_t)(tbase + tok) * D_ + hb + i4);
    const size_t cb = ((size_t)c * 16 + h) * 4096;
#pragma unroll
    for (int q = 0; q < 4; q++) {
        const int jr = (tid >> 4) + q * 16;
        *(float4*)&Sl[jr][i4] = *(const float4*)(SstT + cb + (size_t)jr * 64 + i4);
    }
    __syncthreads();
    float4 acc = *(const float4*)(olbuf + (size_t)(tbase + tok) * D_ + hb + i4);
#pragma unroll 8
    for (int j = 0; j < 64; j++) {
        const float zv = zl[tok][j];
        const float4 p4 = *(const float4*)&Sl[j][i4];
        acc.x = fmaf(zv, p4.x, acc.x);
        acc.y = fmaf(zv, p4.y, acc.y);
        acc.z = fmaf(zv, p4.z, acc.z);
        acc.w = fmaf(zv, p4.w, acc.w);
    }
    *(float4*)(o + (size_t)(tbase + tok) * D_ + hb + i4) = acc;
}

// ---------------------------------------------------------------------------
// bonus + gate: og = bf16((o + (sum_j r*k*r_k) * v) * g). One wave per (t,h).
// ---------------------------------------------------------------------------
__global__ __launch_bounds__(64) void bonus_kernel(const float* __restrict__ o,
                                                   const float* __restrict__ r,
                                                   const float* __restrict__ k,
                                                   const float* __restrict__ v,
                                                   const float* __restrict__ g,
                                                   const float* __restrict__ r_k,
                                                   ushort* __restrict__ og) {
    const int b = blockIdx.x;
    const int t = b >> 4, h = b & 15;
    const int lane = threadIdx.x;
    const size_t idx = (size_t)t * D_ + h * N_ + lane;
    float c = r[idx] * k[idx] * r_k[h * N_ + lane];
    c += __shfl_xor(c, 1);
    c += __shfl_xor(c, 2);
    c += __shfl_xor(c, 4);
    c += __shfl_xor(c, 8);
    c += __shfl_xor(c, 16);
    c += __shfl_xor(c, 32);
    const float on = o[idx] + c * v[idx];
    og[idx] = f2bf(on * g[idx]);
}

// h = gate * up (both bf16), in place into gate
__global__ __launch_bounds__(256) void mulb_kernel(ushort* __restrict__ a, const ushort* __restrict__ b) {
    const int i = blockIdx.x * 256 + threadIdx.x;
    ushort4 av = ((ushort4*)a)[i];
    ushort4 bv = ((const ushort4*)b)[i];
    ushort4 o;
    o.x = f2bf(bf2f(av.x) * bf2f(bv.x));
    o.y = f2bf(bf2f(av.y) * bf2f(bv.y));
    o.z = f2bf(bf2f(av.z) * bf2f(bv.z));
    o.w = f2bf(bf2f(av.w) * bf2f(bv.w));
    ((ushort4*)a)[i] = o;
}

// ---------------------------------------------------------------------------
static inline void tc(const float* in, ushort* out, int K, int N, hipStream_t s) {
    dim3 g(N / 32, K / 32);
    transpose_cast<<<g, 256, 0, s>>>(in, out, K, N);
}
template <typename OutT>
static inline void mm(const ushort* A, const ushort* BT, OutT* C, int M, int Ntot, int K, int epi,
                      const float* res, const float* res2, const float* bias, hipStream_t s) {
    dim3 g((Ntot + 127) / 128, M / 128);
    mfma_gemm<OutT><<<g, 256, 0, s>>>(A, BT, C, res, res2, bias, M, Ntot, K, epi);
}

extern "C" void kernel_launch(void* const* d_in, const int* in_sizes, int n_in,
                              void* d_out, int out_size, void* d_ws, size_t ws_size,
                              hipStream_t stream) {
    const float* x      = (const float*)d_in[0];
    const float* x_prev = (const float*)d_in[1];
    const float* v_first= (const float*)d_in[2];
    const float* state  = (const float*)d_in[3];
    const float* ln1_w  = (const float*)d_in[4];
    const float* ln2_w  = (const float*)d_in[5];
    const float* x_r    = (const float*)d_in[6];
    const float* x_w    = (const float*)d_in[7];
    const float* x_k    = (const float*)d_in[8];
    const float* x_v    = (const float*)d_in[9];
    const float* x_a    = (const float*)d_in[10];
    const float* x_g    = (const float*)d_in[11];
    const float* w0     = (const float*)d_in[12];
    const float* w1     = (const float*)d_in[13];
    const float* w2     = (const float*)d_in[14];
    const float* a0     = (const float*)d_in[15];
    const float* a1     = (const float*)d_in[16];
    const float* a2     = (const float*)d_in[17];
    const float* v0     = (const float*)d_in[18];
    const float* v1     = (const float*)d_in[19];
    const float* v2     = (const float*)d_in[20];
    const float* g1     = (const float*)d_in[21];
    const float* g2     = (const float*)d_in[22];
    const float* k_k    = (const float*)d_in[23];
    const float* k_a    = (const float*)d_in[24];
    const float* r_k    = (const float*)d_in[25];
    const float* R_     = (const float*)d_in[26];
    const float* K_     = (const float*)d_in[27];
    const float* V_     = (const float*)d_in[28];
    const float* O_     = (const float*)d_in[29];
    const float* gate_w = (const float*)d_in[30];
    const float* up_w   = (const float*)d_in[31];
    const float* down_w = (const float*)d_in[32];

    float* ws = (float*)d_ws;
    const size_t U = (size_t)T_ * D_;  // 2M floats
    // fp32 scan-side buffers
    float* u_r  = ws;
    float* u_k  = ws + 1 * U;
    float* u_v  = ws + 2 * U;
    float* u_dc = ws + 3 * U;   // decay; later SstT
    float* u_kk = ws + 4 * U;   // kk;    later o (fix output)
    float* u_mb = ws + 5 * U;   // -kk*a
    float* u_g  = ws + 6 * U;
    float* u_ao = ws + 7 * U;   // a_sig; later Pbuf
    // bf16 activation region: 6 slots of T*D shorts
    ushort* XB = (ushort*)(ws + 8 * U);
    const size_t TD = U;
    ushort* XR = XB + 0 * TD;
    ushort* XW = XB + 1 * TD;
    ushort* XK = XB + 2 * TD;
    ushort* XV = XB + 3 * TD;
    ushort* XA = XB + 4 * TD;
    ushort* XG = XB + 5 * TD;
    ushort* XM   = XB + 0 * TD;  // reuse XR after r-GEMM
    ushort* OG   = XB + 1 * TD;  // reuse XW after w-LoRA1
    ushort* GATE = XB + 2 * TD;  // reuse XK..XG after scan fix
    ushort* UPB  = (ushort*)ws;  // overlay u_r..u_k after bonus
    // chunked-scan overlays
    float* Pbuf  = u_ao;               // [32,16,64,64]
    float* Lbuf  = (float*)XB;         // slots 0-1 (XR/XW dead by pass1)
    float* zbuf  = (float*)(XB + 2 * TD);  // slots 2-3
    float* olbuf = (float*)(XB + 4 * TD);  // slots 4-5
    float* SstT  = u_dc;
    float* obuf  = u_kk;
    // transposed bf16 weights
    ushort* WT = (ushort*)(ws + 11 * U);
    const size_t DD = (size_t)D_ * D_;
    const size_t DF = (size_t)D_ * F_;
    ushort* WTR = WT;
    ushort* WTK = WTR + DD;
    ushort* WTV = WTK + DD;
    ushort* WTO = WTV + DD;
    ushort* WTG = WTO + DD;
    ushort* WTU = WTG + DF;
    ushort* WTD = WTU + DF;
    ushort* WTw1 = WTD + DF;
    ushort* WTw2 = WTw1 + 64 * 1024;
    ushort* WTa1 = WTw2 + 64 * 1024;
    ushort* WTa2 = WTa1 + 64 * 1024;
    ushort* WTv1 = WTa2 + 64 * 1024;
    ushort* WTv2 = WTv1 + 32 * 1024;
    ushort* WTg1 = WTv2 + 32 * 1024;
    ushort* WTg2 = WTg1 + 128 * 1024;
    ushort* Lw = WTg2 + 128 * 1024;
    ushort* La = Lw + (size_t)T_ * 64;
    ushort* Lv = La + (size_t)T_ * 64;
    ushort* Lg = Lv + (size_t)T_ * 32;

    float* out_x = (float*)d_out;
    float* out_xn_last = out_x + (size_t)T_ * D_;
    float* out_state = out_xn_last + D_;

    // --- weight transposes ---
    tc(R_, WTR, D_, D_, stream);
    tc(K_, WTK, D_, D_, stream);
    tc(V_, WTV, D_, D_, stream);
    tc(O_, WTO, D_, D_, stream);
    tc(gate_w, WTG, D_, F_, stream);
    tc(up_w, WTU, D_, F_, stream);
    tc(down_w, WTD, F_, D_, stream);
    tc(w1, WTw1, D_, 64, stream);
    tc(w2, WTw2, 64, D_, stream);
    tc(a1, WTa1, D_, 64, stream);
    tc(a2, WTa2, 64, D_, stream);
    tc(v1, WTv1, D_, 32, stream);
    tc(v2, WTv2, 32, D_, stream);
    tc(g1, WTg1, D_, 128, stream);
    tc(g2, WTg2, 128, D_, stream);

    // 1. ln1 -> xn (in d_out) + xn_last
    rmsnorm_kernel<float><<<T_, 256, 0, stream>>>(x, ln1_w, out_x, out_xn_last);
    // 2. token shift -> bf16 xr..xg
    shift_kernel<<<T_, 256, 0, stream>>>(out_x, x_prev, x_r, x_w, x_k, x_v, x_a, x_g,
                                         XR, XW, XK, XV, XA, XG);
    // 3-5. r/k/v projections
    mm<float>(XR, WTR, u_r, T_, D_, D_, 0, nullptr, nullptr, nullptr, stream);
    mm<float>(XK, WTK, u_k, T_, D_, D_, 0, nullptr, nullptr, nullptr, stream);
    mm<float>(XV, WTV, u_v, T_, D_, D_, 0, nullptr, nullptr, nullptr, stream);
    // 6. LoRA stage-1
    mm<ushort>(XW, WTw1, Lw, T_, 64, D_, 3, nullptr, nullptr, nullptr, stream);   // tanh
    mm<ushort>(XA, WTa1, La, T_, 64, D_, 0, nullptr, nullptr, nullptr, stream);
    mm<ushort>(XV, WTv1, Lv, T_, 32, D_, 0, nullptr, nullptr, nullptr, stream);
    mm<ushort>(XG, WTg1, Lg, T_, 128, D_, 4, nullptr, nullptr, nullptr, stream);  // sigmoid
    // 7. LoRA stage-2 fused epilogues
    mm<float>(Lw, WTw2, u_dc, T_, D_, 64, 6, nullptr, nullptr, w0, stream);       // decay
    mm<float>(La, WTa2, u_ao, T_, D_, 64, 5, nullptr, nullptr, a0, stream);       // a_sig
    mm<float>(Lv, WTv2, u_v, T_, D_, 32, 7, u_v, v_first, v0, stream);            // v lerp
    mm<float>(Lg, WTg2, u_g, T_, D_, 128, 0, nullptr, nullptr, nullptr, stream);  // g
    // 8. kk / mb / k-mod
    kk_kernel<<<T_ * H_, 64, 0, stream>>>(u_k, u_ao, k_k, k_a, u_kk, u_mb);
    // 9. chunked scan (lane-=row pass1)
    scan_pass1<<<NCHUNK * H_ * 2, 64, 0, stream>>>(u_r, u_dc, u_k, u_v, u_kk, u_mb,
                                                   Pbuf, Lbuf, zbuf, olbuf);
    scan_combine<<<H_ * 4, 256, 0, stream>>>(state, Pbuf, Lbuf, SstT, out_state);
    scan_fix<<<(T_ / 16) * H_, 256, 0, stream>>>(zbuf, olbuf, SstT, obuf);
    // 10. bonus + gate -> OG bf16
    bonus_kernel<<<T_ * H_, 64, 0, stream>>>(obuf, u_r, u_k, u_v, u_g, r_k, OG);
    // 11. x1 = x + og@O_ -> d_out
    mm<float>(OG, WTO, out_x, T_, D_, D_, 1, x, nullptr, nullptr, stream);
    // 12. ln2 -> xm bf16
    rmsnorm_kernel<ushort><<<T_, 256, 0, stream>>>(out_x, ln2_w, XM, nullptr);
    // 13. MLP
    mm<ushort>(XM, WTG, GATE, T_, F_, D_, 2, nullptr, nullptr, nullptr, stream);  // silu
    mm<ushort>(XM, WTU, UPB, T_, F_, D_, 0, nullptr, nullptr, nullptr, stream);
    mulb_kernel<<<(T_ * F_ / 4) / 256, 256, 0, stream>>>(GATE, UPB);
    // 14. out = x1 + h@down_w
    mm<float>(GATE, WTD, out_x, T_, D_, F_, 1, out_x, nullptr, nullptr, stream);
}

// Round 5
// 1140.112 us; speedup vs baseline: 1.0097x; 1.0097x over previous
//
#include <hip/hip_runtime.h>
#include <math.h>

// Problem constants (B=1)
#define T_ 2048
#define D_ 1024
#define H_ 16
#define N_ 64
#define F_ 4096
#define NCHUNK 32
#define CLEN 64

typedef __attribute__((ext_vector_type(8))) short bf16x8;
typedef __attribute__((ext_vector_type(4))) float f32x4;

static __device__ __forceinline__ float sigf(float x) { return 1.0f / (1.0f + __expf(-x)); }

static __device__ __forceinline__ ushort f2bf(float f) {
    union { float f; unsigned u; } c; c.f = f;
    unsigned r = (c.u + 0x7FFFu + ((c.u >> 16) & 1u)) >> 16;
    return (ushort)r;
}
static __device__ __forceinline__ float bf2f(ushort h) {
    union { unsigned u; float f; } c; c.u = ((unsigned)h) << 16;
    return c.f;
}

static __device__ __forceinline__ void st4(float* p, float4 v) { *(float4*)p = v; }
static __device__ __forceinline__ void st4(ushort* p, float4 v) {
    ushort4 o; o.x = f2bf(v.x); o.y = f2bf(v.y); o.z = f2bf(v.z); o.w = f2bf(v.w);
    *(ushort4*)p = o;
}
static __device__ __forceinline__ void stC(float* p, float v) { *p = v; }
static __device__ __forceinline__ void stC(ushort* p, float v) { *p = f2bf(v); }

// ---------------------------------------------------------------------------
// RMSNorm: one block per token row. out = w * x * rsqrt(mean(x^2)+eps)
// ---------------------------------------------------------------------------
template <typename OutT>
__global__ __launch_bounds__(256) void rmsnorm_kernel(const float* __restrict__ x,
                                                      const float* __restrict__ w,
                                                      OutT* __restrict__ out,
                                                      float* __restrict__ last) {
    const int t = blockIdx.x;
    const int tid = threadIdx.x;
    const float4* xr = (const float4*)(x + (size_t)t * D_);
    float4 v = xr[tid];
    float ss = v.x * v.x + v.y * v.y + v.z * v.z + v.w * v.w;
    ss += __shfl_xor(ss, 1);
    ss += __shfl_xor(ss, 2);
    ss += __shfl_xor(ss, 4);
    ss += __shfl_xor(ss, 8);
    ss += __shfl_xor(ss, 16);
    ss += __shfl_xor(ss, 32);
    __shared__ float red[4];
    if ((tid & 63) == 0) red[tid >> 6] = ss;
    __syncthreads();
    float tot = red[0] + red[1] + red[2] + red[3];
    float scale = rsqrtf(tot * (1.0f / (float)D_) + 1e-6f);
    float4 wv = ((const float4*)w)[tid];
    float4 o;
    o.x = wv.x * v.x * scale;
    o.y = wv.y * v.y * scale;
    o.z = wv.z * v.z * scale;
    o.w = wv.w * v.w * scale;
    st4(out + (size_t)t * D_ + tid * 4, o);
    if (last != nullptr && t == T_ - 1) ((float4*)last)[tid] = o;
}

// ---------------------------------------------------------------------------
// Token shift -> six bf16 activation buffers (GEMM A operands).
// ---------------------------------------------------------------------------
__global__ __launch_bounds__(256) void shift_kernel(
    const float* __restrict__ xn, const float* __restrict__ x_prev,
    const float* __restrict__ cr, const float* __restrict__ cw, const float* __restrict__ ck,
    const float* __restrict__ cv, const float* __restrict__ ca, const float* __restrict__ cg,
    ushort* __restrict__ xr, ushort* __restrict__ xw, ushort* __restrict__ xk,
    ushort* __restrict__ xv, ushort* __restrict__ xa, ushort* __restrict__ xg) {
    const int i = blockIdx.x * 256 + threadIdx.x;  // float4 index over T*256
    const int t = i >> 8, j = i & 255;
    const float4* xn4 = (const float4*)xn;
    float4 cur = xn4[i];
    float4 prev = (t == 0) ? ((const float4*)x_prev)[j] : xn4[i - 256];
    float4 xx;
    xx.x = prev.x - cur.x;
    xx.y = prev.y - cur.y;
    xx.z = prev.z - cur.z;
    xx.w = prev.w - cur.w;
#define APPLY(dst, c)                                   \
    {                                                   \
        float4 cc = ((const float4*)c)[j];              \
        float4 o;                                       \
        o.x = cur.x + xx.x * cc.x;                      \
        o.y = cur.y + xx.y * cc.y;                      \
        o.z = cur.z + xx.z * cc.z;                      \
        o.w = cur.w + xx.w * cc.w;                      \
        st4(dst + (size_t)i * 4, o);                    \
    }
    APPLY(xr, cr)
    APPLY(xw, cw)
    APPLY(xk, ck)
    APPLY(xv, cv)
    APPLY(xa, ca)
    APPLY(xg, cg)
#undef APPLY
}

// ---------------------------------------------------------------------------
// Weight transpose + cast: in [K,N] fp32 -> out [N,K] bf16. 32x32 tiles.
// ---------------------------------------------------------------------------
__global__ __launch_bounds__(256) void transpose_cast(const float* __restrict__ in,
                                                      ushort* __restrict__ out, int K, int N) {
    __shared__ float tile[32][33];
    const int tx = threadIdx.x & 31, ty = threadIdx.x >> 5;  // 32 x 8
    const int n0 = blockIdx.x * 32, k0 = blockIdx.y * 32;
#pragma unroll
    for (int i = 0; i < 4; i++)
        tile[ty + i * 8][tx] = in[(size_t)(k0 + ty + i * 8) * N + n0 + tx];
    __syncthreads();
#pragma unroll
    for (int i = 0; i < 4; i++)
        out[(size_t)(n0 + ty + i * 8) * K + k0 + tx] = f2bf(tile[tx][ty + i * 8]);
}

// ---------------------------------------------------------------------------
// bf16 MFMA GEMM: C[M,Ntot] = epi(A[M,K] @ BT[Ntot,K]^T).
// 128x128 tile, block 256 (4 waves, 2x2), BK=32, mfma_f32_16x16x32_bf16.
// epi: 0 none, 1 +res, 2 silu, 3 tanh, 4 sig(v), 5 sig(bias+v),
//      6 exp(-e^-0.5*sig(bias+v)) [decay], 7 res+(res2-res)*sig(bias+v) [vlerp]
// ---------------------------------------------------------------------------
template <typename OutT>
__global__ __launch_bounds__(256) void mfma_gemm(
    const ushort* __restrict__ A, const ushort* __restrict__ BT, OutT* __restrict__ C,
    const float* __restrict__ res, const float* __restrict__ res2, const float* __restrict__ bias,
    int M, int Ntot, int K, int epi) {
    __shared__ ushort As[128 * 40];
    __shared__ ushort Bs[128 * 40];
    const int tid = threadIdx.x;
    const int wave = tid >> 6, lane = tid & 63;
    const int wr = wave >> 1, wc = wave & 1;
    const int lrow = lane & 15, quad = lane >> 4;
    const int m0 = blockIdx.y * 128, n0 = blockIdx.x * 128;
    const int sr = tid >> 2;           // staging row 0..63 (and +64)
    const int sc = (tid & 3) << 3;     // staging k offset in elements {0,8,16,24}

    f32x4 acc[4][4] = {};

    for (int k0 = 0; k0 < K; k0 += 32) {
        const float4 av0 = *(const float4*)(A + (size_t)(m0 + sr) * K + k0 + sc);
        const float4 av1 = *(const float4*)(A + (size_t)(m0 + sr + 64) * K + k0 + sc);
        float4 bv0 = make_float4(0.f, 0.f, 0.f, 0.f);
        float4 bv1 = make_float4(0.f, 0.f, 0.f, 0.f);
        if (n0 + sr < Ntot) bv0 = *(const float4*)(BT + (size_t)(n0 + sr) * K + k0 + sc);
        if (n0 + sr + 64 < Ntot) bv1 = *(const float4*)(BT + (size_t)(n0 + sr + 64) * K + k0 + sc);
        __syncthreads();  // previous iter's LDS reads done
        *(float4*)&As[sr * 40 + sc] = av0;
        *(float4*)&As[(sr + 64) * 40 + sc] = av1;
        *(float4*)&Bs[sr * 40 + sc] = bv0;
        *(float4*)&Bs[(sr + 64) * 40 + sc] = bv1;
        __syncthreads();
        bf16x8 af[4], bfr[4];
#pragma unroll
        for (int mi = 0; mi < 4; mi++)
            af[mi] = *(const bf16x8*)&As[(wr * 64 + mi * 16 + lrow) * 40 + quad * 8];
#pragma unroll
        for (int ni = 0; ni < 4; ni++)
            bfr[ni] = *(const bf16x8*)&Bs[(wc * 64 + ni * 16 + lrow) * 40 + quad * 8];
#pragma unroll
        for (int mi = 0; mi < 4; mi++)
#pragma unroll
            for (int ni = 0; ni < 4; ni++)
                acc[mi][ni] = __builtin_amdgcn_mfma_f32_16x16x32_bf16(af[mi], bfr[ni], acc[mi][ni], 0, 0, 0);
    }

#pragma unroll
    for (int mi = 0; mi < 4; mi++) {
#pragma unroll
        for (int r = 0; r < 4; r++) {
            const int row = m0 + wr * 64 + mi * 16 + quad * 4 + r;
#pragma unroll
            for (int ni = 0; ni < 4; ni++) {
                const int col = n0 + wc * 64 + ni * 16 + lrow;
                if (col < Ntot) {
                    const size_t idx = (size_t)row * Ntot + col;
                    float val = acc[mi][ni][r];
                    switch (epi) {
                        case 1: val += res[idx]; break;
                        case 2: val = val * sigf(val); break;
                        case 3: val = tanhf(val); break;
                        case 4: val = sigf(val); break;
                        case 5: val = sigf(bias[col] + val); break;
                        case 6: val = __expf(-0.60653065971263342f * sigf(bias[col] + val)); break;
                        case 7: {
                            float vr = res[idx];
                            val = vr + (res2[idx] - vr) * sigf(bias[col] + val);
                        } break;
                        default: break;
                    }
                    stC(&C[idx], val);
                }
            }
        }
    }
}

// ---------------------------------------------------------------------------
// kk = normalize_per_head(k * k_k); mb = -kk*a_sig; k *= (1+(a-1)*k_a).
// ---------------------------------------------------------------------------
__global__ __launch_bounds__(64) void kk_kernel(float* __restrict__ k,
                                                const float* __restrict__ a_sig,
                                                const float* __restrict__ k_k,
                                                const float* __restrict__ k_a,
                                                float* __restrict__ kk,
                                                float* __restrict__ mb) {
    const int b = blockIdx.x;
    const int t = b >> 4, h = b & 15;
    const int lane = threadIdx.x;
    const size_t idx = (size_t)t * D_ + h * N_ + lane;
    const int wi = h * N_ + lane;
    const float kraw = k[idx];
    const float kv = kraw * k_k[wi];
    float ss = kv * kv;
    ss += __shfl_xor(ss, 1);
    ss += __shfl_xor(ss, 2);
    ss += __shfl_xor(ss, 4);
    ss += __shfl_xor(ss, 8);
    ss += __shfl_xor(ss, 16);
    ss += __shfl_xor(ss, 32);
    const float nrm = fmaxf(sqrtf(ss), 1e-12f);
    const float kkn = kv / nrm;
    kk[idx] = kkn;
    mb[idx] = -kkn * a_sig[idx];
    k[idx] = kraw * (1.0f + (a_sig[idx] - 1.0f) * k_a[wi]);
}

// ---------------------------------------------------------------------------
// Chunked scan pass 1, lane = row layout, state FORCED into registers.
// One wave per (chunk, head, {P|L}): lane i owns row i of the 64x64 matrix in
// 16 named f32x4 registers (no alloca -> no spill; R4 spilled float s[64] at
// VGPR_Count=44 -> 10k cyc/step scratch round-trips). Coefficient vectors are
// wave-uniform per step -> scalar loads. launch_bounds(64,1) lifts the VGPR cap.
// ---------------------------------------------------------------------------
#define FOR16(M) M(0) M(1) M(2) M(3) M(4) M(5) M(6) M(7) \
                 M(8) M(9) M(10) M(11) M(12) M(13) M(14) M(15)

__global__ __launch_bounds__(64, 1) void scan_pass1(
    const float* __restrict__ gR, const float* __restrict__ gD, const float* __restrict__ gK,
    const float* __restrict__ gV, const float* __restrict__ gKK, const float* __restrict__ gMB,
    float* __restrict__ Pbuf, float* __restrict__ Lbuf,
    float* __restrict__ zbuf, float* __restrict__ olbuf) {
    const int bid = blockIdx.x;
    const bool isp = bid & 1;
    const int h = (bid >> 1) & 15;
    const int c = bid >> 5;
    const int lane = threadIdx.x;  // row index
    const int hb = h * N_;
    const int t0 = c * CLEN;

    const float fid = isp ? 1.0f : 0.0f;
#define DECL(q) f32x4 s##q = {(lane == 4 * q + 0) ? fid : 0.0f, \
                              (lane == 4 * q + 1) ? fid : 0.0f, \
                              (lane == 4 * q + 2) ? fid : 0.0f, \
                              (lane == 4 * q + 3) ? fid : 0.0f};
    FOR16(DECL)
#undef DECL

    float* __restrict__ dotOut = isp ? zbuf : olbuf;

    for (int t = t0; t < t0 + CLEN; t++) {
        const float* __restrict__ cD = gD + (size_t)t * D_ + hb;
        const float* __restrict__ cK = gK + (size_t)t * D_ + hb;
        const float* __restrict__ cKK = gKK + (size_t)t * D_ + hb;
        const float* __restrict__ cMB = gMB + (size_t)t * D_ + hb;
        const float* __restrict__ cR = gR + (size_t)t * D_ + hb;

        // pass A: sap = sum_j s[j] * kk[j]  (in-lane, 16-way ILP)
        f32x4 sacc = {0.f, 0.f, 0.f, 0.f};
#define PA(q) { const f32x4 kk4 = *(const f32x4*)(cKK + 4 * q); sacc += s##q * kk4; }
        FOR16(PA)
#undef PA
        const float sap = (sacc.x + sacc.y) + (sacc.z + sacc.w);
        const float vv = isp ? 0.0f : gV[(size_t)t * D_ + hb + lane];

        // pass B: s = s*d + (sap*mb + vv*k); o += s*r
        f32x4 oacc = {0.f, 0.f, 0.f, 0.f};
#define PB(q) {                                                   \
        const f32x4 d4 = *(const f32x4*)(cD + 4 * q);             \
        const f32x4 k4 = *(const f32x4*)(cK + 4 * q);             \
        const f32x4 m4 = *(const f32x4*)(cMB + 4 * q);            \
        const f32x4 r4 = *(const f32x4*)(cR + 4 * q);             \
        s##q = s##q * d4 + (m4 * sap + k4 * vv);                  \
        oacc += s##q * r4;                                        \
    }
        FOR16(PB)
#undef PB
        dotOut[(size_t)t * D_ + hb + lane] = (oacc.x + oacc.y) + (oacc.z + oacc.w);
    }

    float* __restrict__ sd = isp ? Pbuf : Lbuf;
    const size_t base = ((size_t)c * 16 + h) * 4096 + (size_t)lane * 64;
#define ST(q) *(f32x4*)(sd + base + 4 * q) = s##q;
    FOR16(ST)
#undef ST
}

// ---------------------------------------------------------------------------
// Serial chunk combine: S_{c+1} = S_c @ P_c + L_c, S_0 = state_in.
// Stores S_start (transposed) per chunk for the fix pass; final -> state_out.
// Grid 64 = 16 heads x 4 row-groups of 16 rows.
// ---------------------------------------------------------------------------
__global__ __launch_bounds__(256) void scan_combine(
    const float* __restrict__ state_in, const float* __restrict__ Pbuf,
    const float* __restrict__ Lbuf, float* __restrict__ SstT, float* __restrict__ state_out) {
    const int h = blockIdx.x >> 2, rg = blockIdx.x & 3;
    const int tid = threadIdx.x;
    const int i = tid >> 4, j4 = (tid & 15) << 2;
    const int gi = rg * 16 + i;
    __shared__ float Sl[16][68];
    __shared__ float Pl[64][68];

    float4 sv = *(const float4*)(state_in + (size_t)h * 4096 + gi * 64 + j4);
    *(float4*)&Sl[i][j4] = sv;
    __syncthreads();

    for (int c = 0; c < NCHUNK; c++) {
        const size_t cb = ((size_t)c * 16 + h) * 4096;
        float4 scur = *(const float4*)&Sl[i][j4];
        // store S_start transposed: SstT[j][i] = S[i][j]
        SstT[cb + (size_t)(j4 + 0) * 64 + gi] = scur.x;
        SstT[cb + (size_t)(j4 + 1) * 64 + gi] = scur.y;
        SstT[cb + (size_t)(j4 + 2) * 64 + gi] = scur.z;
        SstT[cb + (size_t)(j4 + 3) * 64 + gi] = scur.w;
        // stage P_c
#pragma unroll
        for (int q = 0; q < 4; q++) {
            const int pr = (tid >> 4) + q * 16;
            *(float4*)&Pl[pr][j4] = *(const float4*)(Pbuf + cb + (size_t)pr * 64 + j4);
        }
        __syncthreads();
        float4 acc = *(const float4*)(Lbuf + cb + (size_t)gi * 64 + j4);
#pragma unroll 8
        for (int m = 0; m < 64; m++) {
            const float smv = Sl[i][m];
            const float4 p4 = *(const float4*)&Pl[m][j4];
            acc.x = fmaf(smv, p4.x, acc.x);
            acc.y = fmaf(smv, p4.y, acc.y);
            acc.z = fmaf(smv, p4.z, acc.z);
            acc.w = fmaf(smv, p4.w, acc.w);
        }
        __syncthreads();
        *(float4*)&Sl[i][j4] = acc;
        __syncthreads();
    }
    *(float4*)(state_out + (size_t)h * 4096 + gi * 64 + j4) = *(const float4*)&Sl[i][j4];
}

// ---------------------------------------------------------------------------
// Fix pass: o[t] = o_local[t] + S_start_c @ z[t] (per head).
// Grid 2048 = 128 token-groups (16 tokens) x 16 heads.
// ---------------------------------------------------------------------------
__global__ __launch_bounds__(256) void scan_fix(
    const float* __restrict__ zbuf, const float* __restrict__ olbuf,
    const float* __restrict__ SstT, float* __restrict__ o) {
    const int tg = blockIdx.x >> 4, h = blockIdx.x & 15;
    const int hb = h * N_;
    const int tid = threadIdx.x;
    const int tok = tid >> 4, i4 = (tid & 15) << 2;
    const int tbase = tg * 16;
    const int c = tbase >> 6;
    __shared__ float zl[16][68];
    __shared__ float Sl[64][68];

    *(float4*)&zl[tok][i4] = *(const float4*)(zbuf + (size_t)(tbase + tok) * D_ + hb + i4);
    const size_t cb = ((size_t)c * 16 + h) * 4096;
#pragma unroll
    for (int q = 0; q < 4; q++) {
        const int jr = (tid >> 4) + q * 16;
        *(float4*)&Sl[jr][i4] = *(const float4*)(SstT + cb + (size_t)jr * 64 + i4);
    }
    __syncthreads();
    float4 acc = *(const float4*)(olbuf + (size_t)(tbase + tok) * D_ + hb + i4);
#pragma unroll 8
    for (int j = 0; j < 64; j++) {
        const float zv = zl[tok][j];
        const float4 p4 = *(const float4*)&Sl[j][i4];
        acc.x = fmaf(zv, p4.x, acc.x);
        acc.y = fmaf(zv, p4.y, acc.y);
        acc.z = fmaf(zv, p4.z, acc.z);
        acc.w = fmaf(zv, p4.w, acc.w);
    }
    *(float4*)(o + (size_t)(tbase + tok) * D_ + hb + i4) = acc;
}

// ---------------------------------------------------------------------------
// bonus + gate: og = bf16((o + (sum_j r*k*r_k) * v) * g). One wave per (t,h).
// ---------------------------------------------------------------------------
__global__ __launch_bounds__(64) void bonus_kernel(const float* __restrict__ o,
                                                   const float* __restrict__ r,
                                                   const float* __restrict__ k,
                                                   const float* __restrict__ v,
                                                   const float* __restrict__ g,
                                                   const float* __restrict__ r_k,
                                                   ushort* __restrict__ og) {
    const int b = blockIdx.x;
    const int t = b >> 4, h = b & 15;
    const int lane = threadIdx.x;
    const size_t idx = (size_t)t * D_ + h * N_ + lane;
    float c = r[idx] * k[idx] * r_k[h * N_ + lane];
    c += __shfl_xor(c, 1);
    c += __shfl_xor(c, 2);
    c += __shfl_xor(c, 4);
    c += __shfl_xor(c, 8);
    c += __shfl_xor(c, 16);
    c += __shfl_xor(c, 32);
    const float on = o[idx] + c * v[idx];
    og[idx] = f2bf(on * g[idx]);
}

// h = gate * up (both bf16), in place into gate
__global__ __launch_bounds__(256) void mulb_kernel(ushort* __restrict__ a, const ushort* __restrict__ b) {
    const int i = blockIdx.x * 256 + threadIdx.x;
    ushort4 av = ((ushort4*)a)[i];
    ushort4 bv = ((const ushort4*)b)[i];
    ushort4 o;
    o.x = f2bf(bf2f(av.x) * bf2f(bv.x));
    o.y = f2bf(bf2f(av.y) * bf2f(bv.y));
    o.z = f2bf(bf2f(av.z) * bf2f(bv.z));
    o.w = f2bf(bf2f(av.w) * bf2f(bv.w));
    ((ushort4*)a)[i] = o;
}

// ---------------------------------------------------------------------------
static inline void tc(const float* in, ushort* out, int K, int N, hipStream_t s) {
    dim3 g(N / 32, K / 32);
    transpose_cast<<<g, 256, 0, s>>>(in, out, K, N);
}
template <typename OutT>
static inline void mm(const ushort* A, const ushort* BT, OutT* C, int M, int Ntot, int K, int epi,
                      const float* res, const float* res2, const float* bias, hipStream_t s) {
    dim3 g((Ntot + 127) / 128, M / 128);
    mfma_gemm<OutT><<<g, 256, 0, s>>>(A, BT, C, res, res2, bias, M, Ntot, K, epi);
}

extern "C" void kernel_launch(void* const* d_in, const int* in_sizes, int n_in,
                              void* d_out, int out_size, void* d_ws, size_t ws_size,
                              hipStream_t stream) {
    const float* x      = (const float*)d_in[0];
    const float* x_prev = (const float*)d_in[1];
    const float* v_first= (const float*)d_in[2];
    const float* state  = (const float*)d_in[3];
    const float* ln1_w  = (const float*)d_in[4];
    const float* ln2_w  = (const float*)d_in[5];
    const float* x_r    = (const float*)d_in[6];
    const float* x_w    = (const float*)d_in[7];
    const float* x_k    = (const float*)d_in[8];
    const float* x_v    = (const float*)d_in[9];
    const float* x_a    = (const float*)d_in[10];
    const float* x_g    = (const float*)d_in[11];
    const float* w0     = (const float*)d_in[12];
    const float* w1     = (const float*)d_in[13];
    const float* w2     = (const float*)d_in[14];
    const float* a0     = (const float*)d_in[15];
    const float* a1     = (const float*)d_in[16];
    const float* a2     = (const float*)d_in[17];
    const float* v0     = (const float*)d_in[18];
    const float* v1     = (const float*)d_in[19];
    const float* v2     = (const float*)d_in[20];
    const float* g1     = (const float*)d_in[21];
    const float* g2     = (const float*)d_in[22];
    const float* k_k    = (const float*)d_in[23];
    const float* k_a    = (const float*)d_in[24];
    const float* r_k    = (const float*)d_in[25];
    const float* R_     = (const float*)d_in[26];
    const float* K_     = (const float*)d_in[27];
    const float* V_     = (const float*)d_in[28];
    const float* O_     = (const float*)d_in[29];
    const float* gate_w = (const float*)d_in[30];
    const float* up_w   = (const float*)d_in[31];
    const float* down_w = (const float*)d_in[32];

    float* ws = (float*)d_ws;
    const size_t U = (size_t)T_ * D_;  // 2M floats
    // fp32 scan-side buffers
    float* u_r  = ws;
    float* u_k  = ws + 1 * U;
    float* u_v  = ws + 2 * U;
    float* u_dc = ws + 3 * U;   // decay; later SstT
    float* u_kk = ws + 4 * U;   // kk;    later o (fix output)
    float* u_mb = ws + 5 * U;   // -kk*a
    float* u_g  = ws + 6 * U;
    float* u_ao = ws + 7 * U;   // a_sig; later Pbuf
    // bf16 activation region: 6 slots of T*D shorts
    ushort* XB = (ushort*)(ws + 8 * U);
    const size_t TD = U;
    ushort* XR = XB + 0 * TD;
    ushort* XW = XB + 1 * TD;
    ushort* XK = XB + 2 * TD;
    ushort* XV = XB + 3 * TD;
    ushort* XA = XB + 4 * TD;
    ushort* XG = XB + 5 * TD;
    ushort* XM   = XB + 0 * TD;  // reuse XR after r-GEMM
    ushort* OG   = XB + 1 * TD;  // reuse XW after w-LoRA1
    ushort* GATE = XB + 2 * TD;  // reuse XK..XG after scan fix
    ushort* UPB  = (ushort*)ws;  // overlay u_r..u_k after bonus
    // chunked-scan overlays
    float* Pbuf  = u_ao;               // [32,16,64,64]
    float* Lbuf  = (float*)XB;         // slots 0-1 (XR/XW dead by pass1)
    float* zbuf  = (float*)(XB + 2 * TD);  // slots 2-3
    float* olbuf = (float*)(XB + 4 * TD);  // slots 4-5
    float* SstT  = u_dc;
    float* obuf  = u_kk;
    // transposed bf16 weights
    ushort* WT = (ushort*)(ws + 11 * U);
    const size_t DD = (size_t)D_ * D_;
    const size_t DF = (size_t)D_ * F_;
    ushort* WTR = WT;
    ushort* WTK = WTR + DD;
    ushort* WTV = WTK + DD;
    ushort* WTO = WTV + DD;
    ushort* WTG = WTO + DD;
    ushort* WTU = WTG + DF;
    ushort* WTD = WTU + DF;
    ushort* WTw1 = WTD + DF;
    ushort* WTw2 = WTw1 + 64 * 1024;
    ushort* WTa1 = WTw2 + 64 * 1024;
    ushort* WTa2 = WTa1 + 64 * 1024;
    ushort* WTv1 = WTa2 + 64 * 1024;
    ushort* WTv2 = WTv1 + 32 * 1024;
    ushort* WTg1 = WTv2 + 32 * 1024;
    ushort* WTg2 = WTg1 + 128 * 1024;
    ushort* Lw = WTg2 + 128 * 1024;
    ushort* La = Lw + (size_t)T_ * 64;
    ushort* Lv = La + (size_t)T_ * 64;
    ushort* Lg = Lv + (size_t)T_ * 32;

    float* out_x = (float*)d_out;
    float* out_xn_last = out_x + (size_t)T_ * D_;
    float* out_state = out_xn_last + D_;

    // --- weight transposes ---
    tc(R_, WTR, D_, D_, stream);
    tc(K_, WTK, D_, D_, stream);
    tc(V_, WTV, D_, D_, stream);
    tc(O_, WTO, D_, D_, stream);
    tc(gate_w, WTG, D_, F_, stream);
    tc(up_w, WTU, D_, F_, stream);
    tc(down_w, WTD, F_, D_, stream);
    tc(w1, WTw1, D_, 64, stream);
    tc(w2, WTw2, 64, D_, stream);
    tc(a1, WTa1, D_, 64, stream);
    tc(a2, WTa2, 64, D_, stream);
    tc(v1, WTv1, D_, 32, stream);
    tc(v2, WTv2, 32, D_, stream);
    tc(g1, WTg1, D_, 128, stream);
    tc(g2, WTg2, 128, D_, stream);

    // 1. ln1 -> xn (in d_out) + xn_last
    rmsnorm_kernel<float><<<T_, 256, 0, stream>>>(x, ln1_w, out_x, out_xn_last);
    // 2. token shift -> bf16 xr..xg
    shift_kernel<<<T_, 256, 0, stream>>>(out_x, x_prev, x_r, x_w, x_k, x_v, x_a, x_g,
                                         XR, XW, XK, XV, XA, XG);
    // 3-5. r/k/v projections
    mm<float>(XR, WTR, u_r, T_, D_, D_, 0, nullptr, nullptr, nullptr, stream);
    mm<float>(XK, WTK, u_k, T_, D_, D_, 0, nullptr, nullptr, nullptr, stream);
    mm<float>(XV, WTV, u_v, T_, D_, D_, 0, nullptr, nullptr, nullptr, stream);
    // 6. LoRA stage-1
    mm<ushort>(XW, WTw1, Lw, T_, 64, D_, 3, nullptr, nullptr, nullptr, stream);   // tanh
    mm<ushort>(XA, WTa1, La, T_, 64, D_, 0, nullptr, nullptr, nullptr, stream);
    mm<ushort>(XV, WTv1, Lv, T_, 32, D_, 0, nullptr, nullptr, nullptr, stream);
    mm<ushort>(XG, WTg1, Lg, T_, 128, D_, 4, nullptr, nullptr, nullptr, stream);  // sigmoid
    // 7. LoRA stage-2 fused epilogues
    mm<float>(Lw, WTw2, u_dc, T_, D_, 64, 6, nullptr, nullptr, w0, stream);       // decay
    mm<float>(La, WTa2, u_ao, T_, D_, 64, 5, nullptr, nullptr, a0, stream);       // a_sig
    mm<float>(Lv, WTv2, u_v, T_, D_, 32, 7, u_v, v_first, v0, stream);            // v lerp
    mm<float>(Lg, WTg2, u_g, T_, D_, 128, 0, nullptr, nullptr, nullptr, stream);  // g
    // 8. kk / mb / k-mod
    kk_kernel<<<T_ * H_, 64, 0, stream>>>(u_k, u_ao, k_k, k_a, u_kk, u_mb);
    // 9. chunked scan (lane=row pass1, register state)
    scan_pass1<<<NCHUNK * H_ * 2, 64, 0, stream>>>(u_r, u_dc, u_k, u_v, u_kk, u_mb,
                                                   Pbuf, Lbuf, zbuf, olbuf);
    scan_combine<<<H_ * 4, 256, 0, stream>>>(state, Pbuf, Lbuf, SstT, out_state);
    scan_fix<<<(T_ / 16) * H_, 256, 0, stream>>>(zbuf, olbuf, SstT, obuf);
    // 10. bonus + gate -> OG bf16
    bonus_kernel<<<T_ * H_, 64, 0, stream>>>(obuf, u_r, u_k, u_v, u_g, r_k, OG);
    // 11. x1 = x + og@O_ -> d_out
    mm<float>(OG, WTO, out_x, T_, D_, D_, 1, x, nullptr, nullptr, stream);
    // 12. ln2 -> xm bf16
    rmsnorm_kernel<ushort><<<T_, 256, 0, stream>>>(out_x, ln2_w, XM, nullptr);
    // 13. MLP
    mm<ushort>(XM, WTG, GATE, T_, F_, D_, 2, nullptr, nullptr, nullptr, stream);  // silu
    mm<ushort>(XM, WTU, UPB, T_, F_, D_, 0, nullptr, nullptr, nullptr, stream);
    mulb_kernel<<<(T_ * F_ / 4) / 256, 256, 0, stream>>>(GATE, UPB);
    // 14. out = x1 + h@down_w
    mm<float>(GATE, WTD, out_x, T_, D_, F_, 1, out_x, nullptr, nullptr, stream);
}

// Round 6
// 960.394 us; speedup vs baseline: 1.1986x; 1.1871x over previous
//
#include <hip/hip_runtime.h>
#include <math.h>

// Problem constants (B=1)
#define T_ 2048
#define D_ 1024
#define H_ 16
#define N_ 64
#define F_ 4096
#define NCHUNK 32
#define CLEN 64

typedef __attribute__((ext_vector_type(8))) short bf16x8;
typedef __attribute__((ext_vector_type(4))) float f32x4;
typedef __attribute__((address_space(3))) unsigned int lds_u32_t;
typedef __attribute__((address_space(1))) const unsigned int glb_u32_t;

static __device__ __forceinline__ float sigf(float x) { return 1.0f / (1.0f + __expf(-x)); }

static __device__ __forceinline__ ushort f2bf(float f) {
    union { float f; unsigned u; } c; c.f = f;
    unsigned r = (c.u + 0x7FFFu + ((c.u >> 16) & 1u)) >> 16;
    return (ushort)r;
}
static __device__ __forceinline__ float bf2f(ushort h) {
    union { unsigned u; float f; } c; c.u = ((unsigned)h) << 16;
    return c.f;
}

static __device__ __forceinline__ void st4(float* p, float4 v) { *(float4*)p = v; }
static __device__ __forceinline__ void st4(ushort* p, float4 v) {
    ushort4 o; o.x = f2bf(v.x); o.y = f2bf(v.y); o.z = f2bf(v.z); o.w = f2bf(v.w);
    *(ushort4*)p = o;
}
static __device__ __forceinline__ void stC(float* p, float v) { *p = v; }
static __device__ __forceinline__ void stC(ushort* p, float v) { *p = f2bf(v); }

// ---------------------------------------------------------------------------
// RMSNorm: one block per token row. out = w * x * rsqrt(mean(x^2)+eps)
// ---------------------------------------------------------------------------
template <typename OutT>
__global__ __launch_bounds__(256) void rmsnorm_kernel(const float* __restrict__ x,
                                                      const float* __restrict__ w,
                                                      OutT* __restrict__ out,
                                                      float* __restrict__ last) {
    const int t = blockIdx.x;
    const int tid = threadIdx.x;
    const float4* xr = (const float4*)(x + (size_t)t * D_);
    float4 v = xr[tid];
    float ss = v.x * v.x + v.y * v.y + v.z * v.z + v.w * v.w;
    ss += __shfl_xor(ss, 1);
    ss += __shfl_xor(ss, 2);
    ss += __shfl_xor(ss, 4);
    ss += __shfl_xor(ss, 8);
    ss += __shfl_xor(ss, 16);
    ss += __shfl_xor(ss, 32);
    __shared__ float red[4];
    if ((tid & 63) == 0) red[tid >> 6] = ss;
    __syncthreads();
    float tot = red[0] + red[1] + red[2] + red[3];
    float scale = rsqrtf(tot * (1.0f / (float)D_) + 1e-6f);
    float4 wv = ((const float4*)w)[tid];
    float4 o;
    o.x = wv.x * v.x * scale;
    o.y = wv.y * v.y * scale;
    o.z = wv.z * v.z * scale;
    o.w = wv.w * v.w * scale;
    st4(out + (size_t)t * D_ + tid * 4, o);
    if (last != nullptr && t == T_ - 1) ((float4*)last)[tid] = o;
}

// ---------------------------------------------------------------------------
// Token shift -> six bf16 activation buffers (GEMM A operands).
// ---------------------------------------------------------------------------
__global__ __launch_bounds__(256) void shift_kernel(
    const float* __restrict__ xn, const float* __restrict__ x_prev,
    const float* __restrict__ cr, const float* __restrict__ cw, const float* __restrict__ ck,
    const float* __restrict__ cv, const float* __restrict__ ca, const float* __restrict__ cg,
    ushort* __restrict__ xr, ushort* __restrict__ xw, ushort* __restrict__ xk,
    ushort* __restrict__ xv, ushort* __restrict__ xa, ushort* __restrict__ xg) {
    const int i = blockIdx.x * 256 + threadIdx.x;  // float4 index over T*256
    const int t = i >> 8, j = i & 255;
    const float4* xn4 = (const float4*)xn;
    float4 cur = xn4[i];
    float4 prev = (t == 0) ? ((const float4*)x_prev)[j] : xn4[i - 256];
    float4 xx;
    xx.x = prev.x - cur.x;
    xx.y = prev.y - cur.y;
    xx.z = prev.z - cur.z;
    xx.w = prev.w - cur.w;
#define APPLY(dst, c)                                   \
    {                                                   \
        float4 cc = ((const float4*)c)[j];              \
        float4 o;                                       \
        o.x = cur.x + xx.x * cc.x;                      \
        o.y = cur.y + xx.y * cc.y;                      \
        o.z = cur.z + xx.z * cc.z;                      \
        o.w = cur.w + xx.w * cc.w;                      \
        st4(dst + (size_t)i * 4, o);                    \
    }
    APPLY(xr, cr)
    APPLY(xw, cw)
    APPLY(xk, ck)
    APPLY(xv, cv)
    APPLY(xa, ca)
    APPLY(xg, cg)
#undef APPLY
}

// ---------------------------------------------------------------------------
// Weight transpose + cast: in [K,N] fp32 -> out [N,K] bf16. 32x32 tiles.
// ---------------------------------------------------------------------------
__global__ __launch_bounds__(256) void transpose_cast(const float* __restrict__ in,
                                                      ushort* __restrict__ out, int K, int N) {
    __shared__ float tile[32][33];
    const int tx = threadIdx.x & 31, ty = threadIdx.x >> 5;  // 32 x 8
    const int n0 = blockIdx.x * 32, k0 = blockIdx.y * 32;
#pragma unroll
    for (int i = 0; i < 4; i++)
        tile[ty + i * 8][tx] = in[(size_t)(k0 + ty + i * 8) * N + n0 + tx];
    __syncthreads();
#pragma unroll
    for (int i = 0; i < 4; i++)
        out[(size_t)(n0 + ty + i * 8) * K + k0 + tx] = f2bf(tile[tx][ty + i * 8]);
}

// ---------------------------------------------------------------------------
// bf16 MFMA GEMM: C[M,Ntot] = epi(A[M,K] @ BT[Ntot,K]^T).
// 128x128 tile, block 256 (4 waves, 2x2), BK=32, mfma_f32_16x16x32_bf16.
// epi: 0 none, 1 +res, 2 silu, 3 tanh, 4 sig(v), 5 sig(bias+v),
//      6 exp(-e^-0.5*sig(bias+v)) [decay], 7 res+(res2-res)*sig(bias+v) [vlerp]
// ---------------------------------------------------------------------------
template <typename OutT>
__global__ __launch_bounds__(256) void mfma_gemm(
    const ushort* __restrict__ A, const ushort* __restrict__ BT, OutT* __restrict__ C,
    const float* __restrict__ res, const float* __restrict__ res2, const float* __restrict__ bias,
    int M, int Ntot, int K, int epi) {
    __shared__ ushort As[128 * 40];
    __shared__ ushort Bs[128 * 40];
    const int tid = threadIdx.x;
    const int wave = tid >> 6, lane = tid & 63;
    const int wr = wave >> 1, wc = wave & 1;
    const int lrow = lane & 15, quad = lane >> 4;
    const int m0 = blockIdx.y * 128, n0 = blockIdx.x * 128;
    const int sr = tid >> 2;           // staging row 0..63 (and +64)
    const int sc = (tid & 3) << 3;     // staging k offset in elements {0,8,16,24}

    f32x4 acc[4][4] = {};

    for (int k0 = 0; k0 < K; k0 += 32) {
        const float4 av0 = *(const float4*)(A + (size_t)(m0 + sr) * K + k0 + sc);
        const float4 av1 = *(const float4*)(A + (size_t)(m0 + sr + 64) * K + k0 + sc);
        float4 bv0 = make_float4(0.f, 0.f, 0.f, 0.f);
        float4 bv1 = make_float4(0.f, 0.f, 0.f, 0.f);
        if (n0 + sr < Ntot) bv0 = *(const float4*)(BT + (size_t)(n0 + sr) * K + k0 + sc);
        if (n0 + sr + 64 < Ntot) bv1 = *(const float4*)(BT + (size_t)(n0 + sr + 64) * K + k0 + sc);
        __syncthreads();  // previous iter's LDS reads done
        *(float4*)&As[sr * 40 + sc] = av0;
        *(float4*)&As[(sr + 64) * 40 + sc] = av1;
        *(float4*)&Bs[sr * 40 + sc] = bv0;
        *(float4*)&Bs[(sr + 64) * 40 + sc] = bv1;
        __syncthreads();
        bf16x8 af[4], bfr[4];
#pragma unroll
        for (int mi = 0; mi < 4; mi++)
            af[mi] = *(const bf16x8*)&As[(wr * 64 + mi * 16 + lrow) * 40 + quad * 8];
#pragma unroll
        for (int ni = 0; ni < 4; ni++)
            bfr[ni] = *(const bf16x8*)&Bs[(wc * 64 + ni * 16 + lrow) * 40 + quad * 8];
#pragma unroll
        for (int mi = 0; mi < 4; mi++)
#pragma unroll
            for (int ni = 0; ni < 4; ni++)
                acc[mi][ni] = __builtin_amdgcn_mfma_f32_16x16x32_bf16(af[mi], bfr[ni], acc[mi][ni], 0, 0, 0);
    }

#pragma unroll
    for (int mi = 0; mi < 4; mi++) {
#pragma unroll
        for (int r = 0; r < 4; r++) {
            const int row = m0 + wr * 64 + mi * 16 + quad * 4 + r;
#pragma unroll
            for (int ni = 0; ni < 4; ni++) {
                const int col = n0 + wc * 64 + ni * 16 + lrow;
                if (col < Ntot) {
                    const size_t idx = (size_t)row * Ntot + col;
                    float val = acc[mi][ni][r];
                    switch (epi) {
                        case 1: val += res[idx]; break;
                        case 2: val = val * sigf(val); break;
                        case 3: val = tanhf(val); break;
                        case 4: val = sigf(val); break;
                        case 5: val = sigf(bias[col] + val); break;
                        case 6: val = __expf(-0.60653065971263342f * sigf(bias[col] + val)); break;
                        case 7: {
                            float vr = res[idx];
                            val = vr + (res2[idx] - vr) * sigf(bias[col] + val);
                        } break;
                        default: break;
                    }
                    stC(&C[idx], val);
                }
            }
        }
    }
}

// ---------------------------------------------------------------------------
// kk = normalize_per_head(k * k_k); mb = -kk*a_sig; k *= (1+(a-1)*k_a).
// ---------------------------------------------------------------------------
__global__ __launch_bounds__(64) void kk_kernel(float* __restrict__ k,
                                                const float* __restrict__ a_sig,
                                                const float* __restrict__ k_k,
                                                const float* __restrict__ k_a,
                                                float* __restrict__ kk,
                                                float* __restrict__ mb) {
    const int b = blockIdx.x;
    const int t = b >> 4, h = b & 15;
    const int lane = threadIdx.x;
    const size_t idx = (size_t)t * D_ + h * N_ + lane;
    const int wi = h * N_ + lane;
    const float kraw = k[idx];
    const float kv = kraw * k_k[wi];
    float ss = kv * kv;
    ss += __shfl_xor(ss, 1);
    ss += __shfl_xor(ss, 2);
    ss += __shfl_xor(ss, 4);
    ss += __shfl_xor(ss, 8);
    ss += __shfl_xor(ss, 16);
    ss += __shfl_xor(ss, 32);
    const float nrm = fmaxf(sqrtf(ss), 1e-12f);
    const float kkn = kv / nrm;
    kk[idx] = kkn;
    mb[idx] = -kkn * a_sig[idx];
    k[idx] = kraw * (1.0f + (a_sig[idx] - 1.0f) * k_a[wi]);
}

// ---------------------------------------------------------------------------
// Chunked scan pass 1: lane = row, register state, LDS-ring async prefetch.
// One wave per (chunk, head, {P|L}). Per step the 6 coefficient rows (R,D,K,
// KK,MB,V; 256B each) are DMA'd global->LDS with 2 global_load_lds width-16
// instructions into an 8-slot ring, prefetch distance 6; manual
// s_waitcnt vmcnt(12) gates slot readiness (exact at prologue, over-drains 6
// retired ops at steady state). Coefficients are consumed as uniform-address
// ds_read_b128 broadcasts (conflict-free). Role in HIGH grid bit so the P/L
// twins of one (c,h) land on the same XCD and share L2 lines.
// ---------------------------------------------------------------------------
#define FOR16(M) M(0) M(1) M(2) M(3) M(4) M(5) M(6) M(7) \
                 M(8) M(9) M(10) M(11) M(12) M(13) M(14) M(15)
#define PFD 6

__global__ __launch_bounds__(64, 1) void scan_pass1(
    const float* __restrict__ gR, const float* __restrict__ gD, const float* __restrict__ gK,
    const float* __restrict__ gV, const float* __restrict__ gKK, const float* __restrict__ gMB,
    float* __restrict__ Pbuf, float* __restrict__ Lbuf,
    float* __restrict__ zbuf, float* __restrict__ olbuf) {
    const int bid = blockIdx.x;
    const bool isp = bid >= NCHUNK * H_;  // role = high bit (XCD pairing)
    const int sub = isp ? bid - NCHUNK * H_ : bid;
    const int h = sub & 15;
    const int c = sub >> 4;
    const int lane = threadIdx.x;  // row index
    const int hb = h * N_;
    const int t0 = c * CLEN;

    __shared__ __align__(16) unsigned char ring[8 * 2048];

    // per-lane global source pointers for the two staging instructions
    const int rsel = lane >> 4;
    const int sub4 = (lane & 15) << 2;
    const float* p1 = (rsel == 0 ? gR : rsel == 1 ? gD : rsel == 2 ? gK : gKK)
                      + (size_t)t0 * D_ + hb + sub4;
    // lanes 16-31 fetch the V row; lanes 0-15 and 32-63 fetch MB (32-63 land
    // in pad -- same cache lines, idempotent)
    const float* p2 = (rsel == 1 ? gV : gMB) + (size_t)t0 * D_ + hb + sub4;

    const float fid = isp ? 1.0f : 0.0f;
#define DECL(q) f32x4 s##q = {(lane == 4 * q + 0) ? fid : 0.0f, \
                              (lane == 4 * q + 1) ? fid : 0.0f, \
                              (lane == 4 * q + 2) ? fid : 0.0f, \
                              (lane == 4 * q + 3) ? fid : 0.0f};
    FOR16(DECL)
#undef DECL

    float* __restrict__ dotOut = isp ? zbuf : olbuf;

#define ISSUE(tt) {                                                            \
        const int _sl = (tt) & 7;                                              \
        const size_t _adv = (size_t)((tt) - t0) * D_;                          \
        __builtin_amdgcn_global_load_lds((glb_u32_t*)(p1 + _adv),              \
            (lds_u32_t*)(ring + _sl * 2048), 16, 0, 0);                        \
        __builtin_amdgcn_global_load_lds((glb_u32_t*)(p2 + _adv),              \
            (lds_u32_t*)(ring + _sl * 2048 + 1024), 16, 0, 0);                 \
    }

    for (int i = 0; i < PFD; i++) ISSUE(t0 + i);

    for (int t = t0; t < t0 + CLEN; t++) {
        int tpf = t + PFD;
        if (tpf > t0 + CLEN - 1) tpf = t0 + CLEN - 1;  // idempotent tail reloads
        ISSUE(tpf);
        asm volatile("s_waitcnt vmcnt(12)" ::: "memory");

        const unsigned char* sb = ring + (t & 7) * 2048;
        const f32x4* sRr = (const f32x4*)(sb);
        const f32x4* sDr = (const f32x4*)(sb + 256);
        const f32x4* sKr = (const f32x4*)(sb + 512);
        const f32x4* sKKr = (const f32x4*)(sb + 768);
        const f32x4* sMBr = (const f32x4*)(sb + 1024);
        const float* sVr = (const float*)(sb + 1280);

        // pass A: sap = sum_j s[j] * kk[j]  (in-lane, 16-way ILP)
        f32x4 sacc = {0.f, 0.f, 0.f, 0.f};
#define PA(q) { const f32x4 kk4 = sRr ? sKKr[q] : sKKr[q]; sacc += s##q * kk4; }
        FOR16(PA)
#undef PA
        const float sap = (sacc.x + sacc.y) + (sacc.z + sacc.w);
        const float vv = isp ? 0.0f : sVr[lane];

        // pass B: s = s*d + (sap*mb + vv*k); o += s*r
        f32x4 oacc = {0.f, 0.f, 0.f, 0.f};
#define PB(q) {                                                   \
        const f32x4 d4 = sDr[q];                                  \
        const f32x4 k4 = sKr[q];                                  \
        const f32x4 m4 = sMBr[q];                                 \
        const f32x4 r4 = sRr[q];                                  \
        s##q = s##q * d4 + (m4 * sap + k4 * vv);                  \
        oacc += s##q * r4;                                        \
    }
        FOR16(PB)
#undef PB
        dotOut[(size_t)t * D_ + hb + lane] = (oacc.x + oacc.y) + (oacc.z + oacc.w);
    }
#undef ISSUE

    float* __restrict__ sd = isp ? Pbuf : Lbuf;
    const size_t base = ((size_t)c * 16 + h) * 4096 + (size_t)lane * 64;
#define ST(q) *(f32x4*)(sd + base + 4 * q) = s##q;
    FOR16(ST)
#undef ST
}

// ---------------------------------------------------------------------------
// Serial chunk combine: S_{c+1} = S_c @ P_c + L_c, S_0 = state_in.
// Stores S_start (transposed) per chunk for the fix pass; final -> state_out.
// Grid 64 = 16 heads x 4 row-groups of 16 rows.
// ---------------------------------------------------------------------------
__global__ __launch_bounds__(256) void scan_combine(
    const float* __restrict__ state_in, const float* __restrict__ Pbuf,
    const float* __restrict__ Lbuf, float* __restrict__ SstT, float* __restrict__ state_out) {
    const int h = blockIdx.x >> 2, rg = blockIdx.x & 3;
    const int tid = threadIdx.x;
    const int i = tid >> 4, j4 = (tid & 15) << 2;
    const int gi = rg * 16 + i;
    __shared__ float Sl[16][68];
    __shared__ float Pl[64][68];

    float4 sv = *(const float4*)(state_in + (size_t)h * 4096 + gi * 64 + j4);
    *(float4*)&Sl[i][j4] = sv;
    __syncthreads();

    for (int c = 0; c < NCHUNK; c++) {
        const size_t cb = ((size_t)c * 16 + h) * 4096;
        float4 scur = *(const float4*)&Sl[i][j4];
        // store S_start transposed: SstT[j][i] = S[i][j]
        SstT[cb + (size_t)(j4 + 0) * 64 + gi] = scur.x;
        SstT[cb + (size_t)(j4 + 1) * 64 + gi] = scur.y;
        SstT[cb + (size_t)(j4 + 2) * 64 + gi] = scur.z;
        SstT[cb + (size_t)(j4 + 3) * 64 + gi] = scur.w;
        // stage P_c
#pragma unroll
        for (int q = 0; q < 4; q++) {
            const int pr = (tid >> 4) + q * 16;
            *(float4*)&Pl[pr][j4] = *(const float4*)(Pbuf + cb + (size_t)pr * 64 + j4);
        }
        __syncthreads();
        float4 acc = *(const float4*)(Lbuf + cb + (size_t)gi * 64 + j4);
#pragma unroll 8
        for (int m = 0; m < 64; m++) {
            const float smv = Sl[i][m];
            const float4 p4 = *(const float4*)&Pl[m][j4];
            acc.x = fmaf(smv, p4.x, acc.x);
            acc.y = fmaf(smv, p4.y, acc.y);
            acc.z = fmaf(smv, p4.z, acc.z);
            acc.w = fmaf(smv, p4.w, acc.w);
        }
        __syncthreads();
        *(float4*)&Sl[i][j4] = acc;
        __syncthreads();
    }
    *(float4*)(state_out + (size_t)h * 4096 + gi * 64 + j4) = *(const float4*)&Sl[i][j4];
}

// ---------------------------------------------------------------------------
// Fix pass: o[t] = o_local[t] + S_start_c @ z[t] (per head).
// Grid 2048 = 128 token-groups (16 tokens) x 16 heads.
// ---------------------------------------------------------------------------
__global__ __launch_bounds__(256) void scan_fix(
    const float* __restrict__ zbuf, const float* __restrict__ olbuf,
    const float* __restrict__ SstT, float* __restrict__ o) {
    const int tg = blockIdx.x >> 4, h = blockIdx.x & 15;
    const int hb = h * N_;
    const int tid = threadIdx.x;
    const int tok = tid >> 4, i4 = (tid & 15) << 2;
    const int tbase = tg * 16;
    const int c = tbase >> 6;
    __shared__ float zl[16][68];
    __shared__ float Sl[64][68];

    *(float4*)&zl[tok][i4] = *(const float4*)(zbuf + (size_t)(tbase + tok) * D_ + hb + i4);
    const size_t cb = ((size_t)c * 16 + h) * 4096;
#pragma unroll
    for (int q = 0; q < 4; q++) {
        const int jr = (tid >> 4) + q * 16;
        *(float4*)&Sl[jr][i4] = *(const float4*)(SstT + cb + (size_t)jr * 64 + i4);
    }
    __syncthreads();
    float4 acc = *(const float4*)(olbuf + (size_t)(tbase + tok) * D_ + hb + i4);
#pragma unroll 8
    for (int j = 0; j < 64; j++) {
        const float zv = zl[tok][j];
        const float4 p4 = *(const float4*)&Sl[j][i4];
        acc.x = fmaf(zv, p4.x, acc.x);
        acc.y = fmaf(zv, p4.y, acc.y);
        acc.z = fmaf(zv, p4.z, acc.z);
        acc.w = fmaf(zv, p4.w, acc.w);
    }
    *(float4*)(o + (size_t)(tbase + tok) * D_ + hb + i4) = acc;
}

// ---------------------------------------------------------------------------
// bonus + gate: og = bf16((o + (sum_j r*k*r_k) * v) * g). One wave per (t,h).
// ---------------------------------------------------------------------------
__global__ __launch_bounds__(64) void bonus_kernel(const float* __restrict__ o,
                                                   const float* __restrict__ r,
                                                   const float* __restrict__ k,
                                                   const float* __restrict__ v,
                                                   const float* __restrict__ g,
                                                   const float* __restrict__ r_k,
                                                   ushort* __restrict__ og) {
    const int b = blockIdx.x;
    const int t = b >> 4, h = b & 15;
    const int lane = threadIdx.x;
    const size_t idx = (size_t)t * D_ + h * N_ + lane;
    float c = r[idx] * k[idx] * r_k[h * N_ + lane];
    c += __shfl_xor(c, 1);
    c += __shfl_xor(c, 2);
    c += __shfl_xor(c, 4);
    c += __shfl_xor(c, 8);
    c += __shfl_xor(c, 16);
    c += __shfl_xor(c, 32);
    const float on = o[idx] + c * v[idx];
    og[idx] = f2bf(on * g[idx]);
}

// h = gate * up (both bf16), in place into gate
__global__ __launch_bounds__(256) void mulb_kernel(ushort* __restrict__ a, const ushort* __restrict__ b) {
    const int i = blockIdx.x * 256 + threadIdx.x;
    ushort4 av = ((ushort4*)a)[i];
    ushort4 bv = ((const ushort4*)b)[i];
    ushort4 o;
    o.x = f2bf(bf2f(av.x) * bf2f(bv.x));
    o.y = f2bf(bf2f(av.y) * bf2f(bv.y));
    o.z = f2bf(bf2f(av.z) * bf2f(bv.z));
    o.w = f2bf(bf2f(av.w) * bf2f(bv.w));
    ((ushort4*)a)[i] = o;
}

// ---------------------------------------------------------------------------
static inline void tc(const float* in, ushort* out, int K, int N, hipStream_t s) {
    dim3 g(N / 32, K / 32);
    transpose_cast<<<g, 256, 0, s>>>(in, out, K, N);
}
template <typename OutT>
static inline void mm(const ushort* A, const ushort* BT, OutT* C, int M, int Ntot, int K, int epi,
                      const float* res, const float* res2, const float* bias, hipStream_t s) {
    dim3 g((Ntot + 127) / 128, M / 128);
    mfma_gemm<OutT><<<g, 256, 0, s>>>(A, BT, C, res, res2, bias, M, Ntot, K, epi);
}

extern "C" void kernel_launch(void* const* d_in, const int* in_sizes, int n_in,
                              void* d_out, int out_size, void* d_ws, size_t ws_size,
                              hipStream_t stream) {
    const float* x      = (const float*)d_in[0];
    const float* x_prev = (const float*)d_in[1];
    const float* v_first= (const float*)d_in[2];
    const float* state  = (const float*)d_in[3];
    const float* ln1_w  = (const float*)d_in[4];
    const float* ln2_w  = (const float*)d_in[5];
    const float* x_r    = (const float*)d_in[6];
    const float* x_w    = (const float*)d_in[7];
    const float* x_k    = (const float*)d_in[8];
    const float* x_v    = (const float*)d_in[9];
    const float* x_a    = (const float*)d_in[10];
    const float* x_g    = (const float*)d_in[11];
    const float* w0     = (const float*)d_in[12];
    const float* w1     = (const float*)d_in[13];
    const float* w2     = (const float*)d_in[14];
    const float* a0     = (const float*)d_in[15];
    const float* a1     = (const float*)d_in[16];
    const float* a2     = (const float*)d_in[17];
    const float* v0     = (const float*)d_in[18];
    const float* v1     = (const float*)d_in[19];
    const float* v2     = (const float*)d_in[20];
    const float* g1     = (const float*)d_in[21];
    const float* g2     = (const float*)d_in[22];
    const float* k_k    = (const float*)d_in[23];
    const float* k_a    = (const float*)d_in[24];
    const float* r_k    = (const float*)d_in[25];
    const float* R_     = (const float*)d_in[26];
    const float* K_     = (const float*)d_in[27];
    const float* V_     = (const float*)d_in[28];
    const float* O_     = (const float*)d_in[29];
    const float* gate_w = (const float*)d_in[30];
    const float* up_w   = (const float*)d_in[31];
    const float* down_w = (const float*)d_in[32];

    float* ws = (float*)d_ws;
    const size_t U = (size_t)T_ * D_;  // 2M floats
    // fp32 scan-side buffers
    float* u_r  = ws;
    float* u_k  = ws + 1 * U;
    float* u_v  = ws + 2 * U;
    float* u_dc = ws + 3 * U;   // decay; later SstT
    float* u_kk = ws + 4 * U;   // kk;    later o (fix output)
    float* u_mb = ws + 5 * U;   // -kk*a
    float* u_g  = ws + 6 * U;
    float* u_ao = ws + 7 * U;   // a_sig; later Pbuf
    // bf16 activation region: 6 slots of T*D shorts
    ushort* XB = (ushort*)(ws + 8 * U);
    const size_t TD = U;
    ushort* XR = XB + 0 * TD;
    ushort* XW = XB + 1 * TD;
    ushort* XK = XB + 2 * TD;
    ushort* XV = XB + 3 * TD;
    ushort* XA = XB + 4 * TD;
    ushort* XG = XB + 5 * TD;
    ushort* XM   = XB + 0 * TD;  // reuse XR after r-GEMM
    ushort* OG   = XB + 1 * TD;  // reuse XW after w-LoRA1
    ushort* GATE = XB + 2 * TD;  // reuse XK..XG after scan fix
    ushort* UPB  = (ushort*)ws;  // overlay u_r..u_k after bonus
    // chunked-scan overlays
    float* Pbuf  = u_ao;               // [32,16,64,64]
    float* Lbuf  = (float*)XB;         // slots 0-1 (XR/XW dead by pass1)
    float* zbuf  = (float*)(XB + 2 * TD);  // slots 2-3
    float* olbuf = (float*)(XB + 4 * TD);  // slots 4-5
    float* SstT  = u_dc;
    float* obuf  = u_kk;
    // transposed bf16 weights
    ushort* WT = (ushort*)(ws + 11 * U);
    const size_t DD = (size_t)D_ * D_;
    const size_t DF = (size_t)D_ * F_;
    ushort* WTR = WT;
    ushort* WTK = WTR + DD;
    ushort* WTV = WTK + DD;
    ushort* WTO = WTV + DD;
    ushort* WTG = WTO + DD;
    ushort* WTU = WTG + DF;
    ushort* WTD = WTU + DF;
    ushort* WTw1 = WTD + DF;
    ushort* WTw2 = WTw1 + 64 * 1024;
    ushort* WTa1 = WTw2 + 64 * 1024;
    ushort* WTa2 = WTa1 + 64 * 1024;
    ushort* WTv1 = WTa2 + 64 * 1024;
    ushort* WTv2 = WTv1 + 32 * 1024;
    ushort* WTg1 = WTv2 + 32 * 1024;
    ushort* WTg2 = WTg1 + 128 * 1024;
    ushort* Lw = WTg2 + 128 * 1024;
    ushort* La = Lw + (size_t)T_ * 64;
    ushort* Lv = La + (size_t)T_ * 64;
    ushort* Lg = Lv + (size_t)T_ * 32;

    float* out_x = (float*)d_out;
    float* out_xn_last = out_x + (size_t)T_ * D_;
    float* out_state = out_xn_last + D_;

    // --- weight transposes ---
    tc(R_, WTR, D_, D_, stream);
    tc(K_, WTK, D_, D_, stream);
    tc(V_, WTV, D_, D_, stream);
    tc(O_, WTO, D_, D_, stream);
    tc(gate_w, WTG, D_, F_, stream);
    tc(up_w, WTU, D_, F_, stream);
    tc(down_w, WTD, F_, D_, stream);
    tc(w1, WTw1, D_, 64, stream);
    tc(w2, WTw2, 64, D_, stream);
    tc(a1, WTa1, D_, 64, stream);
    tc(a2, WTa2, 64, D_, stream);
    tc(v1, WTv1, D_, 32, stream);
    tc(v2, WTv2, 32, D_, stream);
    tc(g1, WTg1, D_, 128, stream);
    tc(g2, WTg2, 128, D_, stream);

    // 1. ln1 -> xn (in d_out) + xn_last
    rmsnorm_kernel<float><<<T_, 256, 0, stream>>>(x, ln1_w, out_x, out_xn_last);
    // 2. token shift -> bf16 xr..xg
    shift_kernel<<<T_, 256, 0, stream>>>(out_x, x_prev, x_r, x_w, x_k, x_v, x_a, x_g,
                                         XR, XW, XK, XV, XA, XG);
    // 3-5. r/k/v projections
    mm<float>(XR, WTR, u_r, T_, D_, D_, 0, nullptr, nullptr, nullptr, stream);
    mm<float>(XK, WTK, u_k, T_, D_, D_, 0, nullptr, nullptr, nullptr, stream);
    mm<float>(XV, WTV, u_v, T_, D_, D_, 0, nullptr, nullptr, nullptr, stream);
    // 6. LoRA stage-1
    mm<ushort>(XW, WTw1, Lw, T_, 64, D_, 3, nullptr, nullptr, nullptr, stream);   // tanh
    mm<ushort>(XA, WTa1, La, T_, 64, D_, 0, nullptr, nullptr, nullptr, stream);
    mm<ushort>(XV, WTv1, Lv, T_, 32, D_, 0, nullptr, nullptr, nullptr, stream);
    mm<ushort>(XG, WTg1, Lg, T_, 128, D_, 4, nullptr, nullptr, nullptr, stream);  // sigmoid
    // 7. LoRA stage-2 fused epilogues
    mm<float>(Lw, WTw2, u_dc, T_, D_, 64, 6, nullptr, nullptr, w0, stream);       // decay
    mm<float>(La, WTa2, u_ao, T_, D_, 64, 5, nullptr, nullptr, a0, stream);       // a_sig
    mm<float>(Lv, WTv2, u_v, T_, D_, 32, 7, u_v, v_first, v0, stream);            // v lerp
    mm<float>(Lg, WTg2, u_g, T_, D_, 128, 0, nullptr, nullptr, nullptr, stream);  // g
    // 8. kk / mb / k-mod
    kk_kernel<<<T_ * H_, 64, 0, stream>>>(u_k, u_ao, k_k, k_a, u_kk, u_mb);
    // 9. chunked scan (lane=row pass1, LDS-ring async prefetch)
    scan_pass1<<<NCHUNK * H_ * 2, 64, 0, stream>>>(u_r, u_dc, u_k, u_v, u_kk, u_mb,
                                                   Pbuf, Lbuf, zbuf, olbuf);
    scan_combine<<<H_ * 4, 256, 0, stream>>>(state, Pbuf, Lbuf, SstT, out_state);
    scan_fix<<<(T_ / 16) * H_, 256, 0, stream>>>(zbuf, olbuf, SstT, obuf);
    // 10. bonus + gate -> OG bf16
    bonus_kernel<<<T_ * H_, 64, 0, stream>>>(obuf, u_r, u_k, u_v, u_g, r_k, OG);
    // 11. x1 = x + og@O_ -> d_out
    mm<float>(OG, WTO, out_x, T_, D_, D_, 1, x, nullptr, nullptr, stream);
    // 12. ln2 -> xm bf16
    rmsnorm_kernel<ushort><<<T_, 256, 0, stream>>>(out_x, ln2_w, XM, nullptr);
    // 13. MLP
    mm<ushort>(XM, WTG, GATE, T_, F_, D_, 2, nullptr, nullptr, nullptr, stream);  // silu
    mm<ushort>(XM, WTU, UPB, T_, F_, D_, 0, nullptr, nullptr, nullptr, stream);
    mulb_kernel<<<(T_ * F_ / 4) / 256, 256, 0, stream>>>(GATE, UPB);
    // 14. out = x1 + h@down_w
    mm<float>(GATE, WTD, out_x, T_, D_, F_, 1, out_x, nullptr, nullptr, stream);
}

// Round 7
// 858.550 us; speedup vs baseline: 1.3408x; 1.1186x over previous
//
#include <hip/hip_runtime.h>
#include <math.h>

// Problem constants (B=1)
#define T_ 2048
#define D_ 1024
#define H_ 16
#define N_ 64
#define F_ 4096
#define NCHUNK 32
#define CLEN 64

typedef __attribute__((ext_vector_type(8))) short bf16x8;
typedef __attribute__((ext_vector_type(4))) float f32x4;
typedef __attribute__((address_space(3))) unsigned int lds_u32_t;
typedef __attribute__((address_space(1))) const unsigned int glb_u32_t;

static __device__ __forceinline__ float sigf(float x) { return 1.0f / (1.0f + __expf(-x)); }

static __device__ __forceinline__ ushort f2bf(float f) {
    union { float f; unsigned u; } c; c.f = f;
    unsigned r = (c.u + 0x7FFFu + ((c.u >> 16) & 1u)) >> 16;
    return (ushort)r;
}
static __device__ __forceinline__ float bf2f(ushort h) {
    union { unsigned u; float f; } c; c.u = ((unsigned)h) << 16;
    return c.f;
}

static __device__ __forceinline__ void st4(float* p, float4 v) { *(float4*)p = v; }
static __device__ __forceinline__ void st4(ushort* p, float4 v) {
    ushort4 o; o.x = f2bf(v.x); o.y = f2bf(v.y); o.z = f2bf(v.z); o.w = f2bf(v.w);
    *(ushort4*)p = o;
}
static __device__ __forceinline__ void stC(float* p, float v) { *p = v; }
static __device__ __forceinline__ void stC(ushort* p, float v) { *p = f2bf(v); }

// ---------------------------------------------------------------------------
// RMSNorm: one block per token row. out = w * x * rsqrt(mean(x^2)+eps)
// ---------------------------------------------------------------------------
template <typename OutT>
__global__ __launch_bounds__(256) void rmsnorm_kernel(const float* __restrict__ x,
                                                      const float* __restrict__ w,
                                                      OutT* __restrict__ out,
                                                      float* __restrict__ last) {
    const int t = blockIdx.x;
    const int tid = threadIdx.x;
    const float4* xr = (const float4*)(x + (size_t)t * D_);
    float4 v = xr[tid];
    float ss = v.x * v.x + v.y * v.y + v.z * v.z + v.w * v.w;
    ss += __shfl_xor(ss, 1);
    ss += __shfl_xor(ss, 2);
    ss += __shfl_xor(ss, 4);
    ss += __shfl_xor(ss, 8);
    ss += __shfl_xor(ss, 16);
    ss += __shfl_xor(ss, 32);
    __shared__ float red[4];
    if ((tid & 63) == 0) red[tid >> 6] = ss;
    __syncthreads();
    float tot = red[0] + red[1] + red[2] + red[3];
    float scale = rsqrtf(tot * (1.0f / (float)D_) + 1e-6f);
    float4 wv = ((const float4*)w)[tid];
    float4 o;
    o.x = wv.x * v.x * scale;
    o.y = wv.y * v.y * scale;
    o.z = wv.z * v.z * scale;
    o.w = wv.w * v.w * scale;
    st4(out + (size_t)t * D_ + tid * 4, o);
    if (last != nullptr && t == T_ - 1) ((float4*)last)[tid] = o;
}

// ---------------------------------------------------------------------------
// Token shift -> six bf16 activation buffers (GEMM A operands).
// ---------------------------------------------------------------------------
__global__ __launch_bounds__(256) void shift_kernel(
    const float* __restrict__ xn, const float* __restrict__ x_prev,
    const float* __restrict__ cr, const float* __restrict__ cw, const float* __restrict__ ck,
    const float* __restrict__ cv, const float* __restrict__ ca, const float* __restrict__ cg,
    ushort* __restrict__ xr, ushort* __restrict__ xw, ushort* __restrict__ xk,
    ushort* __restrict__ xv, ushort* __restrict__ xa, ushort* __restrict__ xg) {
    const int i = blockIdx.x * 256 + threadIdx.x;  // float4 index over T*256
    const int t = i >> 8, j = i & 255;
    const float4* xn4 = (const float4*)xn;
    float4 cur = xn4[i];
    float4 prev = (t == 0) ? ((const float4*)x_prev)[j] : xn4[i - 256];
    float4 xx;
    xx.x = prev.x - cur.x;
    xx.y = prev.y - cur.y;
    xx.z = prev.z - cur.z;
    xx.w = prev.w - cur.w;
#define APPLY(dst, c)                                   \
    {                                                   \
        float4 cc = ((const float4*)c)[j];              \
        float4 o;                                       \
        o.x = cur.x + xx.x * cc.x;                      \
        o.y = cur.y + xx.y * cc.y;                      \
        o.z = cur.z + xx.z * cc.z;                      \
        o.w = cur.w + xx.w * cc.w;                      \
        st4(dst + (size_t)i * 4, o);                    \
    }
    APPLY(xr, cr)
    APPLY(xw, cw)
    APPLY(xk, ck)
    APPLY(xv, cv)
    APPLY(xa, ca)
    APPLY(xg, cg)
#undef APPLY
}

// ---------------------------------------------------------------------------
// Weight transpose + cast: in [K,N] fp32 -> out [N,K] bf16. 32x32 tiles.
// ---------------------------------------------------------------------------
__global__ __launch_bounds__(256) void transpose_cast(const float* __restrict__ in,
                                                      ushort* __restrict__ out, int K, int N) {
    __shared__ float tile[32][33];
    const int tx = threadIdx.x & 31, ty = threadIdx.x >> 5;  // 32 x 8
    const int n0 = blockIdx.x * 32, k0 = blockIdx.y * 32;
#pragma unroll
    for (int i = 0; i < 4; i++)
        tile[ty + i * 8][tx] = in[(size_t)(k0 + ty + i * 8) * N + n0 + tx];
    __syncthreads();
#pragma unroll
    for (int i = 0; i < 4; i++)
        out[(size_t)(n0 + ty + i * 8) * K + k0 + tx] = f2bf(tile[tx][ty + i * 8]);
}

// ---------------------------------------------------------------------------
// bf16 MFMA GEMM, m97-style global_load_lds staging.
// C[M,Ntot] = epi(A[M,K(slice)] @ BT[Ntot,K]^T). 128x128 tile, block 256
// (4 waves 2x2), BK=32, mfma_f32_16x16x32_bf16. LDS tiles are CONTIGUOUS
// [row][32 shorts] (64B rows) as required by the DMA's wave-uniform-base +
// lane*16 dest rule. Each wave stages 2 A-chunks + 2 B-chunks (16 rows each)
// per K-step with width-16 global_load_lds. OOB B-rows (Ntot<128 tiles) are
// not staged; the resulting garbage columns are never stored.
// Split-K: grid.z slices K; ATOMIC=true accumulates with atomicAdd (linear
// epilogue only; C must be pre-initialized with the residual/zero).
// epi: 0 none, 1 +res, 2 silu, 3 tanh, 4 sig(v), 5 sig(bias+v),
//      6 exp(-e^-0.5*sig(bias+v)) [decay], 7 res+(res2-res)*sig(bias+v) [vlerp]
// ---------------------------------------------------------------------------
template <typename OutT, bool ATOMIC>
__global__ __launch_bounds__(256) void mfma_gemm(
    const ushort* __restrict__ A, const ushort* __restrict__ BT, OutT* __restrict__ C,
    const float* __restrict__ res, const float* __restrict__ res2, const float* __restrict__ bias,
    int M, int Ntot, int K, int klen, int epi) {
    __shared__ ushort As[128 * 32];
    __shared__ ushort Bs[128 * 32];
    const int tid = threadIdx.x;
    const int wave = tid >> 6, lane = tid & 63;
    const int wr = wave >> 1, wc = wave & 1;
    const int lrow = lane & 15, quad = lane >> 4;
    const int m0 = blockIdx.y * 128, n0 = blockIdx.x * 128;
    const int kbase = blockIdx.z * klen;
    const int srow = lane >> 2;          // row within 16-row chunk
    const int scol = (lane & 3) << 3;    // k offset in shorts {0,8,16,24}

    f32x4 acc[4][4] = {};

    for (int k0 = kbase; k0 < kbase + klen; k0 += 32) {
#pragma unroll
        for (int j = 0; j < 2; j++) {
            const int chunk = 2 * wave + j;  // 0..7
            const ushort* ga = A + (size_t)(m0 + chunk * 16 + srow) * K + k0 + scol;
            __builtin_amdgcn_global_load_lds((glb_u32_t*)ga,
                                             (lds_u32_t*)&As[chunk * 512], 16, 0, 0);
            const int brow = n0 + chunk * 16 + srow;
            const ushort* gb = BT + (size_t)brow * K + k0 + scol;
            if (brow < Ntot)
                __builtin_amdgcn_global_load_lds((glb_u32_t*)gb,
                                                 (lds_u32_t*)&Bs[chunk * 512], 16, 0, 0);
        }
        __syncthreads();  // drains vmcnt(0) before barrier -> LDS tiles ready
        bf16x8 af[4], bfr[4];
#pragma unroll
        for (int mi = 0; mi < 4; mi++)
            af[mi] = *(const bf16x8*)&As[(wr * 64 + mi * 16 + lrow) * 32 + quad * 8];
#pragma unroll
        for (int ni = 0; ni < 4; ni++)
            bfr[ni] = *(const bf16x8*)&Bs[(wc * 64 + ni * 16 + lrow) * 32 + quad * 8];
#pragma unroll
        for (int mi = 0; mi < 4; mi++)
#pragma unroll
            for (int ni = 0; ni < 4; ni++)
                acc[mi][ni] = __builtin_amdgcn_mfma_f32_16x16x32_bf16(af[mi], bfr[ni], acc[mi][ni], 0, 0, 0);
        __syncthreads();  // all waves done reading before next overwrite
    }

#pragma unroll
    for (int mi = 0; mi < 4; mi++) {
#pragma unroll
        for (int r = 0; r < 4; r++) {
            const int row = m0 + wr * 64 + mi * 16 + quad * 4 + r;
#pragma unroll
            for (int ni = 0; ni < 4; ni++) {
                const int col = n0 + wc * 64 + ni * 16 + lrow;
                if (col < Ntot) {
                    const size_t idx = (size_t)row * Ntot + col;
                    float val = acc[mi][ni][r];
                    if constexpr (ATOMIC) {
                        atomicAdd((float*)&C[idx], val);
                    } else {
                        switch (epi) {
                            case 1: val += res[idx]; break;
                            case 2: val = val * sigf(val); break;
                            case 3: val = tanhf(val); break;
                            case 4: val = sigf(val); break;
                            case 5: val = sigf(bias[col] + val); break;
                            case 6: val = __expf(-0.60653065971263342f * sigf(bias[col] + val)); break;
                            case 7: {
                                float vr = res[idx];
                                val = vr + (res2[idx] - vr) * sigf(bias[col] + val);
                            } break;
                            default: break;
                        }
                        stC(&C[idx], val);
                    }
                }
            }
        }
    }
}

// ---------------------------------------------------------------------------
// kk = normalize_per_head(k * k_k); mb = -kk*a_sig; k *= (1+(a-1)*k_a).
// ---------------------------------------------------------------------------
__global__ __launch_bounds__(64) void kk_kernel(float* __restrict__ k,
                                                const float* __restrict__ a_sig,
                                                const float* __restrict__ k_k,
                                                const float* __restrict__ k_a,
                                                float* __restrict__ kk,
                                                float* __restrict__ mb) {
    const int b = blockIdx.x;
    const int t = b >> 4, h = b & 15;
    const int lane = threadIdx.x;
    const size_t idx = (size_t)t * D_ + h * N_ + lane;
    const int wi = h * N_ + lane;
    const float kraw = k[idx];
    const float kv = kraw * k_k[wi];
    float ss = kv * kv;
    ss += __shfl_xor(ss, 1);
    ss += __shfl_xor(ss, 2);
    ss += __shfl_xor(ss, 4);
    ss += __shfl_xor(ss, 8);
    ss += __shfl_xor(ss, 16);
    ss += __shfl_xor(ss, 32);
    const float nrm = fmaxf(sqrtf(ss), 1e-12f);
    const float kkn = kv / nrm;
    kk[idx] = kkn;
    mb[idx] = -kkn * a_sig[idx];
    k[idx] = kraw * (1.0f + (a_sig[idx] - 1.0f) * k_a[wi]);
}

// ---------------------------------------------------------------------------
// Chunked scan pass 1: lane = row, register state, LDS-ring async prefetch.
// (unchanged from round 6 — no longer the bottleneck)
// ---------------------------------------------------------------------------
#define FOR16(M) M(0) M(1) M(2) M(3) M(4) M(5) M(6) M(7) \
                 M(8) M(9) M(10) M(11) M(12) M(13) M(14) M(15)
#define PFD 6

__global__ __launch_bounds__(64, 1) void scan_pass1(
    const float* __restrict__ gR, const float* __restrict__ gD, const float* __restrict__ gK,
    const float* __restrict__ gV, const float* __restrict__ gKK, const float* __restrict__ gMB,
    float* __restrict__ Pbuf, float* __restrict__ Lbuf,
    float* __restrict__ zbuf, float* __restrict__ olbuf) {
    const int bid = blockIdx.x;
    const bool isp = bid >= NCHUNK * H_;  // role = high bit (XCD pairing)
    const int sub = isp ? bid - NCHUNK * H_ : bid;
    const int h = sub & 15;
    const int c = sub >> 4;
    const int lane = threadIdx.x;  // row index
    const int hb = h * N_;
    const int t0 = c * CLEN;

    __shared__ __align__(16) unsigned char ring[8 * 2048];

    const int rsel = lane >> 4;
    const int sub4 = (lane & 15) << 2;
    const float* p1 = (rsel == 0 ? gR : rsel == 1 ? gD : rsel == 2 ? gK : gKK)
                      + (size_t)t0 * D_ + hb + sub4;
    const float* p2 = (rsel == 1 ? gV : gMB) + (size_t)t0 * D_ + hb + sub4;

    const float fid = isp ? 1.0f : 0.0f;
#define DECL(q) f32x4 s##q = {(lane == 4 * q + 0) ? fid : 0.0f, \
                              (lane == 4 * q + 1) ? fid : 0.0f, \
                              (lane == 4 * q + 2) ? fid : 0.0f, \
                              (lane == 4 * q + 3) ? fid : 0.0f};
    FOR16(DECL)
#undef DECL

    float* __restrict__ dotOut = isp ? zbuf : olbuf;

#define ISSUE(tt) {                                                            \
        const int _sl = (tt) & 7;                                              \
        const size_t _adv = (size_t)((tt) - t0) * D_;                          \
        __builtin_amdgcn_global_load_lds((glb_u32_t*)(p1 + _adv),              \
            (lds_u32_t*)(ring + _sl * 2048), 16, 0, 0);                        \
        __builtin_amdgcn_global_load_lds((glb_u32_t*)(p2 + _adv),              \
            (lds_u32_t*)(ring + _sl * 2048 + 1024), 16, 0, 0);                 \
    }

    for (int i = 0; i < PFD; i++) ISSUE(t0 + i);

    for (int t = t0; t < t0 + CLEN; t++) {
        int tpf = t + PFD;
        if (tpf > t0 + CLEN - 1) tpf = t0 + CLEN - 1;  // idempotent tail reloads
        ISSUE(tpf);
        asm volatile("s_waitcnt vmcnt(12)" ::: "memory");

        const unsigned char* sb = ring + (t & 7) * 2048;
        const f32x4* sRr = (const f32x4*)(sb);
        const f32x4* sDr = (const f32x4*)(sb + 256);
        const f32x4* sKr = (const f32x4*)(sb + 512);
        const f32x4* sKKr = (const f32x4*)(sb + 768);
        const f32x4* sMBr = (const f32x4*)(sb + 1024);
        const float* sVr = (const float*)(sb + 1280);

        f32x4 sacc = {0.f, 0.f, 0.f, 0.f};
#define PA(q) { const f32x4 kk4 = sKKr[q]; sacc += s##q * kk4; }
        FOR16(PA)
#undef PA
        const float sap = (sacc.x + sacc.y) + (sacc.z + sacc.w);
        const float vv = isp ? 0.0f : sVr[lane];

        f32x4 oacc = {0.f, 0.f, 0.f, 0.f};
#define PB(q) {                                                   \
        const f32x4 d4 = sDr[q];                                  \
        const f32x4 k4 = sKr[q];                                  \
        const f32x4 m4 = sMBr[q];                                 \
        const f32x4 r4 = sRr[q];                                  \
        s##q = s##q * d4 + (m4 * sap + k4 * vv);                  \
        oacc += s##q * r4;                                        \
    }
        FOR16(PB)
#undef PB
        dotOut[(size_t)t * D_ + hb + lane] = (oacc.x + oacc.y) + (oacc.z + oacc.w);
    }
#undef ISSUE

    float* __restrict__ sd = isp ? Pbuf : Lbuf;
    const size_t base = ((size_t)c * 16 + h) * 4096 + (size_t)lane * 64;
#define ST(q) *(f32x4*)(sd + base + 4 * q) = s##q;
    FOR16(ST)
#undef ST
}

// ---------------------------------------------------------------------------
// Serial chunk combine: S_{c+1} = S_c @ P_c + L_c, S_0 = state_in.
// ---------------------------------------------------------------------------
__global__ __launch_bounds__(256) void scan_combine(
    const float* __restrict__ state_in, const float* __restrict__ Pbuf,
    const float* __restrict__ Lbuf, float* __restrict__ SstT, float* __restrict__ state_out) {
    const int h = blockIdx.x >> 2, rg = blockIdx.x & 3;
    const int tid = threadIdx.x;
    const int i = tid >> 4, j4 = (tid & 15) << 2;
    const int gi = rg * 16 + i;
    __shared__ float Sl[16][68];
    __shared__ float Pl[64][68];

    float4 sv = *(const float4*)(state_in + (size_t)h * 4096 + gi * 64 + j4);
    *(float4*)&Sl[i][j4] = sv;
    __syncthreads();

    for (int c = 0; c < NCHUNK; c++) {
        const size_t cb = ((size_t)c * 16 + h) * 4096;
        float4 scur = *(const float4*)&Sl[i][j4];
        SstT[cb + (size_t)(j4 + 0) * 64 + gi] = scur.x;
        SstT[cb + (size_t)(j4 + 1) * 64 + gi] = scur.y;
        SstT[cb + (size_t)(j4 + 2) * 64 + gi] = scur.z;
        SstT[cb + (size_t)(j4 + 3) * 64 + gi] = scur.w;
#pragma unroll
        for (int q = 0; q < 4; q++) {
            const int pr = (tid >> 4) + q * 16;
            *(float4*)&Pl[pr][j4] = *(const float4*)(Pbuf + cb + (size_t)pr * 64 + j4);
        }
        __syncthreads();
        float4 acc = *(const float4*)(Lbuf + cb + (size_t)gi * 64 + j4);
#pragma unroll 8
        for (int m = 0; m < 64; m++) {
            const float smv = Sl[i][m];
            const float4 p4 = *(const float4*)&Pl[m][j4];
            acc.x = fmaf(smv, p4.x, acc.x);
            acc.y = fmaf(smv, p4.y, acc.y);
            acc.z = fmaf(smv, p4.z, acc.z);
            acc.w = fmaf(smv, p4.w, acc.w);
        }
        __syncthreads();
        *(float4*)&Sl[i][j4] = acc;
        __syncthreads();
    }
    *(float4*)(state_out + (size_t)h * 4096 + gi * 64 + j4) = *(const float4*)&Sl[i][j4];
}

// ---------------------------------------------------------------------------
// Fix pass: o[t] = o_local[t] + S_start_c @ z[t] (per head).
// ---------------------------------------------------------------------------
__global__ __launch_bounds__(256) void scan_fix(
    const float* __restrict__ zbuf, const float* __restrict__ olbuf,
    const float* __restrict__ SstT, float* __restrict__ o) {
    const int tg = blockIdx.x >> 4, h = blockIdx.x & 15;
    const int hb = h * N_;
    const int tid = threadIdx.x;
    const int tok = tid >> 4, i4 = (tid & 15) << 2;
    const int tbase = tg * 16;
    const int c = tbase >> 6;
    __shared__ float zl[16][68];
    __shared__ float Sl[64][68];

    *(float4*)&zl[tok][i4] = *(const float4*)(zbuf + (size_t)(tbase + tok) * D_ + hb + i4);
    const size_t cb = ((size_t)c * 16 + h) * 4096;
#pragma unroll
    for (int q = 0; q < 4; q++) {
        const int jr = (tid >> 4) + q * 16;
        *(float4*)&Sl[jr][i4] = *(const float4*)(SstT + cb + (size_t)jr * 64 + i4);
    }
    __syncthreads();
    float4 acc = *(const float4*)(olbuf + (size_t)(tbase + tok) * D_ + hb + i4);
#pragma unroll 8
    for (int j = 0; j < 64; j++) {
        const float zv = zl[tok][j];
        const float4 p4 = *(const float4*)&Sl[j][i4];
        acc.x = fmaf(zv, p4.x, acc.x);
        acc.y = fmaf(zv, p4.y, acc.y);
        acc.z = fmaf(zv, p4.z, acc.z);
        acc.w = fmaf(zv, p4.w, acc.w);
    }
    *(float4*)(o + (size_t)(tbase + tok) * D_ + hb + i4) = acc;
}

// ---------------------------------------------------------------------------
// bonus + gate: og = bf16((o + (sum_j r*k*r_k) * v) * g). One wave per (t,h).
// ---------------------------------------------------------------------------
__global__ __launch_bounds__(64) void bonus_kernel(const float* __restrict__ o,
                                                   const float* __restrict__ r,
                                                   const float* __restrict__ k,
                                                   const float* __restrict__ v,
                                                   const float* __restrict__ g,
                                                   const float* __restrict__ r_k,
                                                   ushort* __restrict__ og) {
    const int b = blockIdx.x;
    const int t = b >> 4, h = b & 15;
    const int lane = threadIdx.x;
    const size_t idx = (size_t)t * D_ + h * N_ + lane;
    float c = r[idx] * k[idx] * r_k[h * N_ + lane];
    c += __shfl_xor(c, 1);
    c += __shfl_xor(c, 2);
    c += __shfl_xor(c, 4);
    c += __shfl_xor(c, 8);
    c += __shfl_xor(c, 16);
    c += __shfl_xor(c, 32);
    const float on = o[idx] + c * v[idx];
    og[idx] = f2bf(on * g[idx]);
}

// H[t,j] = silu(Z[t,j]) * Z[t,j+4096]  (Z = merged [gate|up], [T,8192] bf16)
__global__ __launch_bounds__(256) void mulz_kernel(const ushort* __restrict__ Z,
                                                   ushort* __restrict__ Hb) {
    const int idx = blockIdx.x * 256 + threadIdx.x;  // ushort4 index over T*1024
    const int t = idx >> 10;
    const int j = (idx & 1023) << 2;
    const ushort4 zg = *(const ushort4*)(Z + (size_t)t * 8192 + j);
    const ushort4 zu = *(const ushort4*)(Z + (size_t)t * 8192 + 4096 + j);
    ushort4 o;
    float g0 = bf2f(zg.x), g1 = bf2f(zg.y), g2 = bf2f(zg.z), g3 = bf2f(zg.w);
    o.x = f2bf(g0 * sigf(g0) * bf2f(zu.x));
    o.y = f2bf(g1 * sigf(g1) * bf2f(zu.y));
    o.z = f2bf(g2 * sigf(g2) * bf2f(zu.z));
    o.w = f2bf(g3 * sigf(g3) * bf2f(zu.w));
    *(ushort4*)(Hb + (size_t)t * 4096 + j) = o;
}

// ---------------------------------------------------------------------------
static inline void tc(const float* in, ushort* out, int K, int N, hipStream_t s) {
    dim3 g(N / 32, K / 32);
    transpose_cast<<<g, 256, 0, s>>>(in, out, K, N);
}
template <typename OutT, bool ATOMIC = false>
static inline void mm(const ushort* A, const ushort* BT, OutT* C, int M, int Ntot, int K,
                      int nsplit, int epi, const float* res, const float* res2,
                      const float* bias, hipStream_t s) {
    dim3 g((Ntot + 127) / 128, M / 128, nsplit);
    mfma_gemm<OutT, ATOMIC><<<g, 256, 0, s>>>(A, BT, C, res, res2, bias, M, Ntot, K,
                                              K / nsplit, epi);
}

extern "C" void kernel_launch(void* const* d_in, const int* in_sizes, int n_in,
                              void* d_out, int out_size, void* d_ws, size_t ws_size,
                              hipStream_t stream) {
    const float* x      = (const float*)d_in[0];
    const float* x_prev = (const float*)d_in[1];
    const float* v_first= (const float*)d_in[2];
    const float* state  = (const float*)d_in[3];
    const float* ln1_w  = (const float*)d_in[4];
    const float* ln2_w  = (const float*)d_in[5];
    const float* x_r    = (const float*)d_in[6];
    const float* x_w    = (const float*)d_in[7];
    const float* x_k    = (const float*)d_in[8];
    const float* x_v    = (const float*)d_in[9];
    const float* x_a    = (const float*)d_in[10];
    const float* x_g    = (const float*)d_in[11];
    const float* w0     = (const float*)d_in[12];
    const float* w1     = (const float*)d_in[13];
    const float* w2     = (const float*)d_in[14];
    const float* a0     = (const float*)d_in[15];
    const float* a1     = (const float*)d_in[16];
    const float* a2     = (const float*)d_in[17];
    const float* v0     = (const float*)d_in[18];
    const float* v1     = (const float*)d_in[19];
    const float* v2     = (const float*)d_in[20];
    const float* g1     = (const float*)d_in[21];
    const float* g2     = (const float*)d_in[22];
    const float* k_k    = (const float*)d_in[23];
    const float* k_a    = (const float*)d_in[24];
    const float* r_k    = (const float*)d_in[25];
    const float* R_     = (const float*)d_in[26];
    const float* K_     = (const float*)d_in[27];
    const float* V_     = (const float*)d_in[28];
    const float* O_     = (const float*)d_in[29];
    const float* gate_w = (const float*)d_in[30];
    const float* up_w   = (const float*)d_in[31];
    const float* down_w = (const float*)d_in[32];

    float* ws = (float*)d_ws;
    const size_t U = (size_t)T_ * D_;  // 2M floats
    // fp32 scan-side buffers
    float* u_r  = ws;
    float* u_k  = ws + 1 * U;
    float* u_v  = ws + 2 * U;
    float* u_dc = ws + 3 * U;   // decay; later SstT
    float* u_kk = ws + 4 * U;   // kk;    later o (fix output)
    float* u_mb = ws + 5 * U;   // -kk*a
    float* u_g  = ws + 6 * U;
    float* u_ao = ws + 7 * U;   // a_sig; later Pbuf
    // bf16 activation region: 6 slots of T*D shorts
    ushort* XB = (ushort*)(ws + 8 * U);
    const size_t TD = U;
    ushort* XR = XB + 0 * TD;
    ushort* XW = XB + 1 * TD;
    ushort* XK = XB + 2 * TD;
    ushort* XV = XB + 3 * TD;
    ushort* XA = XB + 4 * TD;
    ushort* XG = XB + 5 * TD;
    ushort* XM   = XB + 0 * TD;        // reuse XR after r-GEMM
    ushort* OG   = XB + 1 * TD;        // reuse XW after w-LoRA1
    ushort* Hbuf = XB + 2 * TD;        // MLP hidden, [T,F] bf16 (slots 2-5, exact)
    ushort* Zbuf = (ushort*)ws;        // merged [gate|up] [T,2F] bf16 (overlays u_r..u_kk, dead)
    // chunked-scan overlays
    float* Pbuf  = u_ao;                   // [32,16,64,64]
    float* Lbuf  = (float*)XB;             // slots 0-1 (XR/XW dead by pass1)
    float* zbuf  = (float*)(XB + 2 * TD);  // slots 2-3
    float* olbuf = (float*)(XB + 4 * TD);  // slots 4-5
    float* SstT  = u_dc;
    float* obuf  = u_kk;
    // transposed bf16 weights
    ushort* WT = (ushort*)(ws + 11 * U);
    const size_t DD = (size_t)D_ * D_;
    const size_t DF = (size_t)D_ * F_;
    ushort* WTR = WT;
    ushort* WTK = WTR + DD;
    ushort* WTV = WTK + DD;
    ushort* WTO = WTV + DD;
    ushort* WTG = WTO + DD;
    ushort* WTU = WTG + DF;   // contiguous after WTG -> merged N=8192 B operand
    ushort* WTD = WTU + DF;
    ushort* WTw1 = WTD + DF;
    ushort* WTw2 = WTw1 + 64 * 1024;
    ushort* WTa1 = WTw2 + 64 * 1024;
    ushort* WTa2 = WTa1 + 64 * 1024;
    ushort* WTv1 = WTa2 + 64 * 1024;
    ushort* WTv2 = WTv1 + 32 * 1024;
    ushort* WTg1 = WTv2 + 32 * 1024;
    ushort* WTg2 = WTg1 + 128 * 1024;
    ushort* Lw = WTg2 + 128 * 1024;
    ushort* La = Lw + (size_t)T_ * 64;
    ushort* Lv = La + (size_t)T_ * 64;
    ushort* Lg = Lv + (size_t)T_ * 32;

    float* out_x = (float*)d_out;
    float* out_xn_last = out_x + (size_t)T_ * D_;
    float* out_state = out_xn_last + D_;

    // --- weight transposes ---
    tc(R_, WTR, D_, D_, stream);
    tc(K_, WTK, D_, D_, stream);
    tc(V_, WTV, D_, D_, stream);
    tc(O_, WTO, D_, D_, stream);
    tc(gate_w, WTG, D_, F_, stream);
    tc(up_w, WTU, D_, F_, stream);
    tc(down_w, WTD, F_, D_, stream);
    tc(w1, WTw1, D_, 64, stream);
    tc(w2, WTw2, 64, D_, stream);
    tc(a1, WTa1, D_, 64, stream);
    tc(a2, WTa2, 64, D_, stream);
    tc(v1, WTv1, D_, 32, stream);
    tc(v2, WTv2, 32, D_, stream);
    tc(g1, WTg1, D_, 128, stream);
    tc(g2, WTg2, 128, D_, stream);

    // 1. ln1 -> xn (in d_out) + xn_last
    rmsnorm_kernel<float><<<T_, 256, 0, stream>>>(x, ln1_w, out_x, out_xn_last);
    // 2. token shift -> bf16 xr..xg
    shift_kernel<<<T_, 256, 0, stream>>>(out_x, x_prev, x_r, x_w, x_k, x_v, x_a, x_g,
                                         XR, XW, XK, XV, XA, XG);
    // 3-5. r/k/v projections, split-K2 atomic (zero-init u_r..u_v first)
    hipMemsetAsync(u_r, 0, 3 * U * sizeof(float), stream);
    mm<float, true>(XR, WTR, u_r, T_, D_, D_, 2, 0, nullptr, nullptr, nullptr, stream);
    mm<float, true>(XK, WTK, u_k, T_, D_, D_, 2, 0, nullptr, nullptr, nullptr, stream);
    mm<float, true>(XV, WTV, u_v, T_, D_, D_, 2, 0, nullptr, nullptr, nullptr, stream);
    // 6. LoRA stage-1
    mm<ushort>(XW, WTw1, Lw, T_, 64, D_, 1, 3, nullptr, nullptr, nullptr, stream);   // tanh
    mm<ushort>(XA, WTa1, La, T_, 64, D_, 1, 0, nullptr, nullptr, nullptr, stream);
    mm<ushort>(XV, WTv1, Lv, T_, 32, D_, 1, 0, nullptr, nullptr, nullptr, stream);
    mm<ushort>(XG, WTg1, Lg, T_, 128, D_, 1, 4, nullptr, nullptr, nullptr, stream);  // sigmoid
    // 7. LoRA stage-2 fused epilogues
    mm<float>(Lw, WTw2, u_dc, T_, D_, 64, 1, 6, nullptr, nullptr, w0, stream);       // decay
    mm<float>(La, WTa2, u_ao, T_, D_, 64, 1, 5, nullptr, nullptr, a0, stream);       // a_sig
    mm<float>(Lv, WTv2, u_v, T_, D_, 32, 1, 7, u_v, v_first, v0, stream);            // v lerp
    mm<float>(Lg, WTg2, u_g, T_, D_, 128, 1, 0, nullptr, nullptr, nullptr, stream);  // g
    // 8. kk / mb / k-mod
    kk_kernel<<<T_ * H_, 64, 0, stream>>>(u_k, u_ao, k_k, k_a, u_kk, u_mb);
    // 9. chunked scan
    scan_pass1<<<NCHUNK * H_ * 2, 64, 0, stream>>>(u_r, u_dc, u_k, u_v, u_kk, u_mb,
                                                   Pbuf, Lbuf, zbuf, olbuf);
    scan_combine<<<H_ * 4, 256, 0, stream>>>(state, Pbuf, Lbuf, SstT, out_state);
    scan_fix<<<(T_ / 16) * H_, 256, 0, stream>>>(zbuf, olbuf, SstT, obuf);
    // 10. bonus + gate -> OG bf16
    bonus_kernel<<<T_ * H_, 64, 0, stream>>>(obuf, u_r, u_k, u_v, u_g, r_k, OG);
    // 11. x1 = x + og@O_ : preload x into out_x, then split-K2 atomic
    hipMemcpyAsync(out_x, x, U * sizeof(float), hipMemcpyDeviceToDevice, stream);
    mm<float, true>(OG, WTO, out_x, T_, D_, D_, 2, 0, nullptr, nullptr, nullptr, stream);
    // 12. ln2 -> xm bf16
    rmsnorm_kernel<ushort><<<T_, 256, 0, stream>>>(out_x, ln2_w, XM, nullptr);
    // 13. MLP: merged gate|up (N=8192, 1024 blocks), swiglu, down split-K4 atomic
    mm<ushort>(XM, WTG, Zbuf, T_, 2 * F_, D_, 1, 0, nullptr, nullptr, nullptr, stream);
    mulz_kernel<<<(T_ * (F_ / 4)) / 256, 256, 0, stream>>>(Zbuf, Hbuf);
    mm<float, true>(Hbuf, WTD, out_x, T_, D_, F_, 4, 0, nullptr, nullptr, nullptr, stream);
}